// Round 18
// baseline (127.613 us; speedup 1.0000x reference)
//
#include <hip/hip_runtime.h>
#include <hip/hip_bf16.h>

typedef unsigned long long u64;
typedef unsigned int u32;

#define A_TOTAL 76725
#define NCLS 90
#define KTOP 5000u
#define MAXT 100
#define KTHR 0x3D4CCCCDu         /* bits of 0.05f */
#define TCAP 2048u               /* per-lane candidate capacity (total) */
#define SCAP 512u                /* per-slice capacity */
#define SELCAP 512u              /* fast-path >=T_b candidate cap */

__device__ __forceinline__ u64 pack_key(u32 k, u32 i) {
  return ((u64)k << 32) | (u64)(0xFFFFFFFFu - i);
}

// Full wave-0 cut with totals: B = smallest bucket with count(>=B) >= need.
__device__ __forceinline__ void cut4096w(const u32* hh, u32 need, int wl,
                                         u32& B, u32& incl, u32& above, u32& total) {
  int lo = wl << 6;
  u32 s = 0;
  #pragma unroll
  for (int j = 0; j < 64; ++j) s += hh[lo + j];
  u32 suf = s;
  #pragma unroll
  for (int off = 1; off < 64; off <<= 1) {
    u32 v = __shfl_down(suf, off, 64);
    if (wl < 64 - off) suf += v;
  }
  total = __shfl(suf, 0, 64);
  if (total < need) { B = 0; incl = total; above = 0; return; }
  u32 sufnext = suf - s;
  bool cross = (suf >= need) && (sufnext < need);
  u64 bal = __ballot(cross);
  int gl = (int)__ffsll((unsigned long long)bal) - 1;
  int glo = gl << 6;
  u32 aboveG = __shfl(sufnext, gl, 64);
  u32 hb = hh[glo + wl];
  u32 sufb = hb;
  #pragma unroll
  for (int off = 1; off < 64; off <<= 1) {
    u32 v = __shfl_down(sufb, off, 64);
    if (wl < 64 - off) sufb += v;
  }
  bool c2 = (aboveG + sufb >= need) && (aboveG + sufb - hb < need);
  u64 bal2 = __ballot(c2);
  int jB = (int)__ffsll((unsigned long long)bal2) - 1;
  B = (u32)(glo + jB);
  incl = aboveG + __shfl(sufb, jB, 64);
  above = incl - __shfl(hb, jB, 64);
}

// Block-cooperative descending bitonic sort of a[0..n) padded to pow2 with 0.
__device__ __forceinline__ void bitonic_desc(u64* a, u32 n, int tid, int nth) {
  u32 P = 2; while (P < n) P <<= 1;
  for (u32 i = tid; i < P; i += nth) if (i >= n) a[i] = 0ULL;
  __syncthreads();
  for (u32 kk = 2; kk <= P; kk <<= 1) {
    for (u32 jj = kk >> 1; jj; jj >>= 1) {
      for (u32 i = tid; i < P; i += nth) {
        u32 ixj = i ^ jj;
        if (ixj > i) {
          u64 x = a[i], y = a[ixj];
          bool up = ((i & kk) == 0);
          if (up ? (x < y) : (x > y)) { a[i] = y; a[ixj] = x; }
        }
      }
      __syncthreads();
    }
  }
}

// Wave-batch bitset greedy NMS over sorted candidates (single wave, no barriers).
__device__ __forceinline__ int bitset_scan(const u64* key_s, const float4* boxes4, size_t bbase,
                                           int C, float4* wbox, float4* bbox,
                                           float* outS, float* outB, int w, int wl) {
  int cur = 0;
  while (w < MAXT && cur < C) {
    int p = cur + wl;
    bool valid = (p < C);
    u64 kk = valid ? key_s[p] : 0ull;
    float4 mybox = make_float4(-3e30f, -3e30f, -3e30f, -3e30f);  // sentinel: zero overlap
    if (valid) {
      u32 idx = 0xFFFFFFFFu - (u32)(kk & 0xFFFFFFFFull);
      mybox = boxes4[bbase + idx];
    }
    bbox[wl] = mybox;
    float myarea = (mybox.z - mybox.x) * (mybox.w - mybox.y);
    bool alive = valid;
    for (int j = 0; j < w; ++j) {
      float4 pb = wbox[j];
      float yy1 = fmaxf(pb.x, mybox.x), xx1 = fmaxf(pb.y, mybox.y);
      float yy2 = fminf(pb.z, mybox.z), xx2 = fminf(pb.w, mybox.w);
      float inter = fmaxf(yy2 - yy1, 0.0f) * fmaxf(xx2 - xx1, 0.0f);
      bool bad = false;
      if (inter > 0.0f) {
        float pa = (pb.z - pb.x) * (pb.w - pb.y);
        bad = inter / (pa + myarea - inter + 1e-8f) > 0.3f;
      }
      alive = alive && !bad;
    }
    u64 krow = 0ull;
    int jmax = C - cur; if (jmax > 64) jmax = 64;
    for (int j = 0; j < jmax; ++j) {
      float4 pb = bbox[j];
      float yy1 = fmaxf(pb.x, mybox.x), xx1 = fmaxf(pb.y, mybox.y);
      float yy2 = fminf(pb.z, mybox.z), xx2 = fminf(pb.w, mybox.w);
      float inter = fmaxf(yy2 - yy1, 0.0f) * fmaxf(xx2 - xx1, 0.0f);
      bool kill = false;
      if (inter > 0.0f) {
        float pa = (pb.z - pb.x) * (pb.w - pb.y);
        kill = inter / (pa + myarea - inter + 1e-8f) > 0.3f;
      }
      if (kill) krow |= (1ull << j);
    }
    u32 krlo = (u32)krow, krhi = (u32)(krow >> 32);
    u64 amask = __ballot(alive);
    int myord = -1;
    while (amask != 0ull && w < MAXT) {
      int js = (int)__ffsll((unsigned long long)amask) - 1;
      u32 klo = __shfl(krlo, js, 64);
      u32 khi = __shfl(krhi, js, 64);
      u64 kr = ((u64)khi << 32) | (u64)klo;
      if (wl == js) myord = w;
      amask &= ~kr;
      amask &= ~(1ull << js);
      w++;
    }
    if (myord >= 0) {
      outS[myord] = __uint_as_float((u32)(kk >> 32));
      *(float4*)(outB + myord * 4) = mybox;
      wbox[myord] = mybox;
    }
    cur += 64;
  }
  return w;
}

// Wave-level lazy greedy NMS (fallback tier only; original semantics).
__device__ __forceinline__ int lazy_scan_g(const u64* key_s, const float4* boxes4, size_t bbase,
                                           int C, float4* wbox, float* outS, float* outB,
                                           int w, int wl) {
  int cur = 0;
  while (w < MAXT && cur < C) {
    int p = cur + wl;
    bool alive = (p < C);
    u64 kk = alive ? key_s[p] : 0ull;
    float4 mybox = make_float4(0.f, 0.f, 0.f, 0.f);
    if (alive) {
      u32 idx = 0xFFFFFFFFu - (u32)(kk & 0xFFFFFFFFull);
      mybox = boxes4[bbase + idx];
    }
    float myarea = (mybox.z - mybox.x) * (mybox.w - mybox.y);
    for (int j = 0; j < w; ++j) {
      float4 pb = wbox[j];
      float yy1 = fmaxf(pb.x, mybox.x), xx1 = fmaxf(pb.y, mybox.y);
      float yy2 = fminf(pb.z, mybox.z), xx2 = fminf(pb.w, mybox.w);
      float inter = fmaxf(yy2 - yy1, 0.0f) * fmaxf(xx2 - xx1, 0.0f);
      bool bad = false;
      if (inter > 0.0f) {
        float pa = (pb.z - pb.x) * (pb.w - pb.y);
        bad = inter / (pa + myarea - inter + 1e-8f) > 0.3f;
      }
      alive = alive && !bad;
    }
    for (;;) {
      u64 bal = __ballot(alive);
      if (bal == 0ull) break;
      int js = (int)__ffsll((unsigned long long)bal) - 1;
      float4 pb;
      pb.x = __shfl(mybox.x, js, 64);
      pb.y = __shfl(mybox.y, js, 64);
      pb.z = __shfl(mybox.z, js, 64);
      pb.w = __shfl(mybox.w, js, 64);
      u64 wk = __shfl(kk, js, 64);
      if (wl == 0) {
        outS[w] = __uint_as_float((u32)(wk >> 32));
        *(float4*)(outB + w * 4) = pb;
        wbox[w] = pb;
      }
      w++;
      if (w >= MAXT) break;
      if (wl <= js) alive = false;
      else if (alive) {
        float yy1 = fmaxf(pb.x, mybox.x), xx1 = fmaxf(pb.y, mybox.y);
        float yy2 = fminf(pb.z, mybox.z), xx2 = fminf(pb.w, mybox.w);
        float inter = fmaxf(yy2 - yy1, 0.0f) * fmaxf(xx2 - xx1, 0.0f);
        if (inter > 0.0f) {
          float pa = (pb.z - pb.x) * (pb.w - pb.y);
          if (inter / (pa + myarea - inter + 1e-8f) > 0.3f) alive = false;
        }
      }
    }
    cur += 64;
  }
  return w;
}

// ---------------- workspace zeroing ----------------
__global__ __launch_bounds__(256) void zero_kernel(u32* __restrict__ p, int n) {
  int i = blockIdx.x * 256 + threadIdx.x;
  if (i < n) p[i] = 0;
}

// ---------------- fused decode+clip (blocks 0..599) and streaming collect (600..4019) ----------------
__device__ __forceinline__ void coll_elem(int i, float x, int b, int base, int slice,
                                          u64* __restrict__ listT_g, u32* __restrict__ cnt_pad) {
  if (x >= 0.0f) {                  // s >= 0.5
    u32 a = (u32)i / 91u;           // compile-time magic-mul
    u32 c = (u32)i - a * 91u;
    if (c != 0u) {
      float s = 1.0f / (1.0f + expf(-x));
      int lane = b * NCLS + (int)c - 1;
      u32 idx = (u32)base + a;
      u32 p = atomicAdd(&cnt_pad[lane * 128 + slice * 16], 1u);
      if (p < SCAP) listT_g[(((size_t)lane * 8 + slice) << 9) + p] = pack_key(__float_as_uint(s), idx);
    }
  }
}

__global__ __launch_bounds__(256) void front_kernel(
    const float* __restrict__ bx0, const float* __restrict__ bx1, const float* __restrict__ bx2,
    const float* __restrict__ bx3, const float* __restrict__ bx4,
    const float* __restrict__ an0, const float* __restrict__ an1, const float* __restrict__ an2,
    const float* __restrict__ an3, const float* __restrict__ an4,
    const float* __restrict__ c3, const float* __restrict__ c4, const float* __restrict__ c5,
    const float* __restrict__ c6, const float* __restrict__ c7,
    const float* __restrict__ img, float* __restrict__ boxes,
    u64* __restrict__ listT_g, u32* __restrict__ cnt_pad)
{
  int blk = blockIdx.x, tid = threadIdx.x;
  if (blk < 600) {
    int t = blk * 256 + tid;
    if (t >= 2 * A_TOTAL) return;
    int b = t / A_TOTAL, a = t % A_TOTAL;
    const float* bp; const float* ap; int al; int nl;
    if (a < 57600)      { bp = bx0; ap = an0; al = a;          nl = 57600; }
    else if (a < 72000) { bp = bx1; ap = an1; al = a - 57600;  nl = 14400; }
    else if (a < 75600) { bp = bx2; ap = an2; al = a - 72000;  nl = 3600;  }
    else if (a < 76500) { bp = bx3; ap = an3; al = a - 75600;  nl = 900;   }
    else                { bp = bx4; ap = an4; al = a - 76500;  nl = 225;   }
    float4 e  = *(const float4*)(bp + ((size_t)b * nl + al) * 4);
    float4 an = *(const float4*)(ap + ((size_t)b * nl + al) * 4);
    const float CLIP = 4.135166556742356f; // log(1000/16)
    float ah  = an.z - an.x + 1.0f;
    float aw  = an.w - an.y + 1.0f;
    float ayc = an.x + 0.5f * ah;
    float axc = an.y + 0.5f * aw;
    float dh = fminf(e.z, CLIP), dw = fminf(e.w, CLIP);
    float yc = e.x * ah + ayc;
    float xc = e.y * aw + axc;
    float h  = expf(dh) * ah;
    float w  = expf(dw) * aw;
    float ymin = yc - 0.5f * h;
    float xmin = xc - 0.5f * w;
    float ymax = ymin + h - 1.0f;
    float xmax = xmin + w - 1.0f;
    float H = img[b * 2 + 0], W = img[b * 2 + 1];
    float4 o;
    o.x = fminf(fmaxf(ymin, 0.0f), H);
    o.y = fminf(fmaxf(xmin, 0.0f), W);
    o.z = fminf(fmaxf(ymax, 0.0f), H);
    o.w = fminf(fmaxf(xmax, 0.0f), W);
    *(float4*)(boxes + (size_t)t * 4) = o;
    return;
  }
  int blk2 = blk - 600;
  int slice = blk2 & 7;
  const float* cls; int n, base, b, loc, J, lvl;
  if (blk2 < 2560)      { lvl = 0; cls = c3; n = 57600; base = 0;     J = 1280; int r = blk2;        b = r >= J; loc = b ? r - J : r; }
  else if (blk2 < 3200) { lvl = 1; cls = c4; n = 14400; base = 57600; J = 320;  int r = blk2 - 2560; b = r >= J; loc = b ? r - J : r; }
  else if (blk2 < 3360) { lvl = 2; cls = c5; n = 3600;  base = 72000; J = 80;   int r = blk2 - 3200; b = r >= J; loc = b ? r - J : r; }
  else if (blk2 < 3400) { lvl = 3; cls = c6; n = 900;   base = 75600; J = 20;   int r = blk2 - 3360; b = r >= J; loc = b ? r - J : r; }
  else                  { lvl = 4; cls = c7; n = 225;   base = 76500; J = 10;   int r = blk2 - 3400; b = r >= J; loc = b ? r - J : r; }

  if (lvl <= 3) {
    int F4 = n * 91 / 4;
    int chunk = (F4 + J - 1) / J;
    int q0 = loc * chunk;
    int q1 = q0 + chunk; if (q1 > F4) q1 = F4;
    const float4* src4 = (const float4*)(cls + (size_t)b * n * 91);
    for (int q = q0 + tid; q < q1; q += 256) {
      float4 v = src4[q];
      int i0 = q << 2;
      coll_elem(i0,     v.x, b, base, slice, listT_g, cnt_pad);
      coll_elem(i0 + 1, v.y, b, base, slice, listT_g, cnt_pad);
      coll_elem(i0 + 2, v.z, b, base, slice, listT_g, cnt_pad);
      coll_elem(i0 + 3, v.w, b, base, slice, listT_g, cnt_pad);
    }
  } else {
    int F = n * 91;                 // 20475 (not /4-divisible) -> scalar
    int chunk = (F + J - 1) / J;
    int s0 = loc * chunk;
    int s1 = s0 + chunk; if (s1 > F) s1 = F;
    const float* src = cls + (size_t)b * F;
    for (int i = s0 + tid; i < s1; i += 256) coll_elem(i, src[i], b, base, slice, listT_g, cnt_pad);
  }
}

// ---------------- phase 1: per-lane top-8 prefix greedy -> true winner subset ----------------
__global__ __launch_bounds__(256) void top8_kernel(
    const u64* __restrict__ listT_g, const u32* __restrict__ cnt_pad,
    const float* __restrict__ boxes, u32* __restrict__ win8, u32* __restrict__ w8cnt)
{
  __shared__ u64 wred[4];
  __shared__ u64 sh_top;
  __shared__ u64 topk[8];
  __shared__ float4 tb[8];
  int tid = threadIdx.x;
  int lane = blockIdx.x;

  u32 pre[9]; pre[0] = 0;
  bool of = false;
  #pragma unroll
  for (int j = 0; j < 8; ++j) {
    u32 cj = cnt_pad[lane * 128 + j * 16];
    of |= (cj > SCAP);
    pre[j + 1] = pre[j] + cj;
  }
  u32 cnt = pre[8];
  if (of || cnt > TCAP) { if (tid == 0) w8cnt[lane] = 0xFFFFu; return; }

  u64 kr[8];
  #pragma unroll
  for (int r = 0; r < 8; ++r) {
    u32 s = (u32)tid + (u32)r * 256u;
    u64 k = 0ull;
    if (s < cnt) {
      u32 j = 0;
      #pragma unroll
      for (int t = 1; t < 8; ++t) if (s >= pre[t]) j = (u32)t;
      k = listT_g[(((size_t)lane * 8 + j) << 9) + (s - pre[j])];
    }
    kr[r] = k;
  }

  int nt = 0;
  for (int it = 0; it < 8; ++it) {
    u64 m = kr[0];
    #pragma unroll
    for (int r = 1; r < 8; ++r) if (kr[r] > m) m = kr[r];
    #pragma unroll
    for (int off = 1; off < 64; off <<= 1) {
      u64 o = __shfl_xor(m, off);
      if (o > m) m = o;
    }
    if ((tid & 63) == 0) wred[tid >> 6] = m;
    __syncthreads();
    if (tid == 0) {
      u64 w = wred[0];
      if (wred[1] > w) w = wred[1];
      if (wred[2] > w) w = wred[2];
      if (wred[3] > w) w = wred[3];
      sh_top = w;
      topk[it] = w;
    }
    __syncthreads();
    u64 ch = sh_top;
    if (ch == 0ull) break;
    #pragma unroll
    for (int r = 0; r < 8; ++r) if (kr[r] == ch) kr[r] = 0ull;   // keys unique
    nt = it + 1;
  }
  __syncthreads();
  const float4* boxes4 = (const float4*)boxes;
  size_t bbase = (size_t)(lane / NCLS) * A_TOTAL;
  if (tid < nt) {
    u32 idx = 0xFFFFFFFFu - (u32)(topk[tid] & 0xFFFFFFFFull);
    tb[tid] = boxes4[bbase + idx];
  }
  __syncthreads();
  if (tid == 0) {
    float4 abox[8];
    int w8 = 0;
    for (int i = 0; i < nt; ++i) {
      float4 mb = tb[i];
      float ma = (mb.z - mb.x) * (mb.w - mb.y);
      bool alive = true;
      for (int j = 0; j < w8; ++j) {
        float4 pb = abox[j];
        float yy1 = fmaxf(pb.x, mb.x), xx1 = fmaxf(pb.y, mb.y);
        float yy2 = fminf(pb.z, mb.z), xx2 = fminf(pb.w, mb.w);
        float inter = fmaxf(yy2 - yy1, 0.0f) * fmaxf(xx2 - xx1, 0.0f);
        if (inter > 0.0f) {
          float pa = (pb.z - pb.x) * (pb.w - pb.y);
          if (inter / (pa + ma - inter + 1e-8f) > 0.3f) alive = false;
        }
      }
      if (alive) {
        win8[lane * 8 + w8] = (u32)(topk[i] >> 32);
        abox[w8] = mb;
        w8++;
      }
    }
    w8cnt[lane] = (u32)w8;
  }
}

// ---------------- phase 2: per-batch T_b = 100th-largest of subset winners ----------------
__global__ __launch_bounds__(256) void tlb2_kernel(const u32* __restrict__ win8,
                                                   const u32* __restrict__ w8cnt,
                                                   u32* __restrict__ tparams)
{
  __shared__ u32 vals[720];
  __shared__ u32 sh_T, sh_tot, sh_panic;
  int t = threadIdx.x;
  if (t == 0) sh_panic = 0;
  __syncthreads();
  for (int b = 0; b < 2; ++b) {
    if (t == 0) { sh_T = 0xFFFFFFFFu; sh_tot = 0; }
    __syncthreads();
    u32 mycnt = 0;
    for (int i = t; i < 720; i += 256) {
      int ln = b * NCLS + i / 8;
      u32 cc = w8cnt[ln];
      u32 v = 0;
      if (cc == 0xFFFFu) { sh_panic = 1; }
      else if ((u32)(i & 7) < cc) { v = win8[ln * 8 + (i & 7)]; mycnt++; }
      vals[i] = v;
    }
    atomicAdd(&sh_tot, mycnt);
    __syncthreads();
    for (int i = t; i < 720; i += 256) {
      u32 v = vals[i];
      if (v) {
        u32 r = 0;
        for (int j = 0; j < 720; ++j) r += (vals[j] > v) ? 1u : 0u;
        if (r <= 99u) atomicMin(&sh_T, v);
      }
    }
    __syncthreads();
    if (t == 0) {
      tparams[b] = sh_T;
      if (sh_tot < 100u || sh_T == 0xFFFFFFFFu) sh_panic = 1;
    }
    __syncthreads();
  }
  if (t == 0) tparams[2] = sh_panic;
}

// ---------------- per-lane NMS: T_b fast path + exact in-kernel fallback ----------------
__global__ __launch_bounds__(256) void nms_kernel(
    const float* __restrict__ c3, const float* __restrict__ c4, const float* __restrict__ c5,
    const float* __restrict__ c6, const float* __restrict__ c7,
    const float* __restrict__ boxes, const u64* __restrict__ listT_g,
    const u32* __restrict__ cnt_pad, const u32* __restrict__ tparams,
    float* __restrict__ nms_s, float* __restrict__ nms_b)
{
  __shared__ __align__(16) char big[40960];     // fallback: listA u64[5120] -> cntArr u32[4096]
  __shared__ __align__(16) u64 listE[2048];     // fallback only
  __shared__ u64 key_s[2048];
  __shared__ __align__(16) u32 histL[4096];     // fallback hist; fast path: sel u64[SELCAP]
  __shared__ float4 wbox[MAXT];
  __shared__ float4 bbox[64];
  __shared__ u32 wtot[4];
  __shared__ u32 sh_flag, sh_cS;
  __shared__ u64 sh_minPrev;
  __shared__ u32 sh_w, sh_done, sh_eidx, sh_Rthr, sh_eSorted, sh_bigF;
  __shared__ u32 sh_B, sh_incl, sh_above, sh_total, sh_cA, sh_cE, sh_B2;

  int tid = threadIdx.x;
  int lane = blockIdx.x;
  int b = lane / NCLS, c = lane % NCLS;
  const float4* boxes4 = (const float4*)boxes;
  size_t bbase = (size_t)b * A_TOTAL;
  const u64 thrpack = ((u64)KTHR) << 32;

  float* outS = nms_s + (size_t)lane * MAXT;
  float* outB = nms_b + (size_t)lane * MAXT * 4;

  u32 pre[9]; pre[0] = 0;
  bool of = false;
  #pragma unroll
  for (int j = 0; j < 8; ++j) {
    u32 cj = cnt_pad[lane * 128 + j * 16];
    of |= (cj > SCAP);
    pre[j + 1] = pre[j] + cj;
  }
  u32 cnt = pre[8];
  u32 Tlb = tparams[b], panic = tparams[2];
  if (tid == 0) { sh_flag = (of || cnt > TCAP || panic) ? 1u : 0u; sh_cS = 0; }
  __syncthreads();

  if (!sh_flag) {
    // fast path: only candidates >= T_b can reach the final per-batch top-100
    const u64 Tpack = ((u64)Tlb) << 32;
    u64* sel = (u64*)histL;
    #pragma unroll
    for (int r = 0; r < 8; ++r) {
      u32 s = (u32)tid + (u32)r * 256u;
      if (s < cnt) {
        u32 j = 0;
        #pragma unroll
        for (int t = 1; t < 8; ++t) if (s >= pre[t]) j = (u32)t;
        u64 k = listT_g[(((size_t)lane * 8 + j) << 9) + (s - pre[j])];
        if (k >= Tpack) {
          u32 p = atomicAdd(&sh_cS, 1u);
          if (p < SELCAP) sel[p] = k;
        }
      }
    }
    __syncthreads();
    u32 Cs = sh_cS;
    if (Cs > SELCAP) {
      if (tid == 0) sh_flag = 1;
    } else {
      for (u32 j = tid; j < Cs; j += 256) {
        u64 kj = sel[j];
        u32 rk = 0;
        for (u32 i2 = 0; i2 < Cs; ++i2) rk += (sel[i2] > kj) ? 1u : 0u;
        key_s[rk] = kj;
      }
      __syncthreads();
      if (tid < 64) {
        int w = bitset_scan(key_s, boxes4, bbase, (int)Cs, wbox, bbox, outS, outB, 0, tid);
        if (tid == 0) sh_w = (u32)w;     // w < MAXT expected: rest provably below final top-100
      }
    }
  }
  __syncthreads();
  if (!sh_flag) {
    u32 w = sh_w;
    for (u32 p = w + (u32)tid; p < MAXT; p += 256) {
      outS[p] = -1.0f;
      *(float4*)(outB + p * 4) = make_float4(0.f, 0.f, 0.f, 0.f);
    }
    return;
  }

  // ================= EXACT FALLBACK (rare): rebuild from raw column =================
  auto sb_of = [&](int i) -> u32 {
    const float* p; int al, nl;
    if (i < 57600)      { p = c3; al = i;          nl = 57600; }
    else if (i < 72000) { p = c4; al = i - 57600;  nl = 14400; }
    else if (i < 75600) { p = c5; al = i - 72000;  nl = 3600;  }
    else if (i < 76500) { p = c6; al = i - 75600;  nl = 900;   }
    else                { p = c7; al = i - 76500;  nl = 225;   }
    float x = p[((size_t)b * nl + al) * 91 + (c + 1)];
    float s = 1.0f / (1.0f + expf(-x));
    return __float_as_uint(s);
  };

  u64* listA = (u64*)big;
  for (int i = tid; i < 4096; i += 256) histL[i] = 0;
  if (tid == 0) {
    sh_cA = 0; sh_cE = 0; sh_w = 0; sh_done = 0; sh_eidx = 0; sh_eSorted = 0; sh_minPrev = ~0ull;
  }
  __syncthreads();
  for (int i = tid; i < A_TOTAL; i += 256) atomicAdd(&histL[sb_of(i) >> 19], 1u);
  __syncthreads();
  if (tid < 64) {
    u32 Bx, ix, ax, tx;
    cut4096w(histL, KTOP, tid, Bx, ix, ax, tx);
    if (tid == 0) sh_B = Bx;
  }
  __syncthreads();
  u32 B = sh_B;
  for (int i = tid; i < A_TOTAL; i += 256) {
    u32 u = sb_of(i);
    u32 bkt = u >> 19;
    if (bkt > B) {
      u32 p = atomicAdd(&sh_cA, 1u);
      if (p < 5120u) listA[p] = pack_key(u, (u32)i);
    } else if (bkt == B) {
      u32 p = atomicAdd(&sh_cE, 1u);
      if (p < 2048u) listE[p] = pack_key(u, (u32)i);
    }
  }
  __syncthreads();
  u32 g = sh_cA, h = sh_cE;
  if (h > 2048u) {
    for (int i = tid; i < 4096; i += 256) histL[i] = 0;
    if (tid == 0) sh_cE = 0;
    __syncthreads();
    for (int i = tid; i < A_TOTAL; i += 256) {
      u32 u = sb_of(i);
      if ((u >> 19) == B) atomicAdd(&histL[(u >> 7) & 0xFFFu], 1u);
    }
    __syncthreads();
    u32 R1 = KTOP - g;
    if (tid < 64) {
      u32 Bx, ix, ax, tx;
      cut4096w(histL, R1, tid, Bx, ix, ax, tx);
      if (tid == 0) sh_B2 = Bx;
    }
    __syncthreads();
    u32 B2 = sh_B2;
    for (int i = tid; i < A_TOTAL; i += 256) {
      u32 u = sb_of(i);
      if ((u >> 19) == B) {
        u32 sb2 = (u >> 7) & 0xFFFu;
        if (sb2 > B2) {
          u32 p = atomicAdd(&sh_cA, 1u);
          if (p < 5120u) listA[p] = pack_key(u, (u32)i);
        } else if (sb2 == B2) {
          u32 p = atomicAdd(&sh_cE, 1u);
          if (p < 2048u) listE[p] = pack_key(u, (u32)i);
        }
      }
    }
    __syncthreads();
    g = sh_cA; h = sh_cE; if (h > 2048u) h = 2048u;
  }
  if (g > 5120u) g = 5120u;
  u32 R = (g < KTOP) ? (KTOP - g) : 0u; if (R > h) R = h;

  u64 ak[20];
  #pragma unroll
  for (int r = 0; r < 20; ++r) {
    u32 s2 = (u32)tid + (u32)r * 256u;
    u64 kp = (s2 < g) ? listA[s2] : 0ull;
    if (kp < thrpack) kp = 0ull;
    ak[r] = kp;
  }
  __syncthreads();
  u32* cntArr = (u32*)big;

  const float LO0  = 0.04f;
  const float INV0 = 4096.0f / (1.001f - 0.04f);

  for (int seg = 0; seg < 7200; ++seg) {
    __syncthreads();
    if (sh_w >= MAXT || sh_done) break;
    u64 minPrev = sh_minPrev;

    int digLvl = 0;
    u32 A_B0 = 0, A_B1 = 0;
    float lo1 = 0.f, inv1 = 0.f;
    u64 kMask = 0, kPref = 0;
    int m1shift = 32;
    int selMode = -1;
    u32 selB = 0;
    u32 C = 0;
    bool fromE = false;

    for (int lvl = 0; lvl < 8; ++lvl) {
      for (int i = tid; i < 4096; i += 256) histL[i] = 0;
      __syncthreads();
      #pragma unroll
      for (int r = 0; r < 20; ++r) {
        u64 k = ak[r];
        if (!k || k >= minPrev) continue;
        float s = __uint_as_float((u32)(k >> 32));
        if (digLvl >= 1) { int d0 = (int)((s - LO0) * INV0); d0 = min(max(d0, 0), 4095); if ((u32)d0 != A_B0) continue; }
        if (digLvl >= 2) { int d1 = (int)((s - lo1) * inv1); d1 = min(max(d1, 0), 4095); if ((u32)d1 != A_B1) continue; }
        if (digLvl >= 3 && ((k & kMask) != kPref)) continue;
        u32 d;
        if (digLvl == 0)      { int t0 = (int)((s - LO0) * INV0); d = (u32)min(max(t0, 0), 4095); }
        else if (digLvl == 1) { int t1 = (int)((s - lo1) * inv1); d = (u32)min(max(t1, 0), 4095); }
        else                  d = (u32)((k >> m1shift) & 0xFFFull);
        atomicAdd(&histL[d], 1u);
      }
      __syncthreads();
      if (tid < 64) {
        u32 Bx, ix, ax, tx;
        cut4096w(histL, 1024u, tid, Bx, ix, ax, tx);
        if (tid == 0) { sh_B = Bx; sh_incl = ix; sh_above = ax; sh_total = tx; }
      }
      __syncthreads();
      u32 total = sh_total, incl = sh_incl, above = sh_above, Bx = sh_B;
      if (total == 0u)   { fromE = true; break; }
      if (total < 1024u) { selMode = 0; C = total; break; }
      if (incl <= 2048u) { selMode = 1; selB = Bx; C = incl; break; }
      if (above > 0u)    { selMode = 2; selB = Bx; C = above; break; }
      if (digLvl == 0) {
        A_B0 = Bx;
        lo1 = LO0 + (float)Bx / INV0;
        inv1 = INV0 * 4096.0f;
        digLvl = 1;
      } else if (digLvl == 1) {
        A_B1 = Bx;
        digLvl = 2; m1shift = 32;
      } else {
        kPref |= ((u64)Bx << m1shift);
        kMask |= (0xFFFull << m1shift);
        m1shift -= 12;
        digLvl++;
      }
      __syncthreads();
    }

    if (fromE) {
      if (!sh_eSorted) {
        bitonic_desc(listE, h, tid, 256);
        if (tid == 0) {
          u32 lo = 0, hi2 = h;
          while (lo < hi2) { u32 mid = (lo + hi2) >> 1; if (listE[mid] >= thrpack) lo = mid + 1; else hi2 = mid; }
          sh_Rthr = (R < lo) ? R : lo;
          sh_eSorted = 1;
        }
        __syncthreads();
      }
      u32 eidx = sh_eidx;
      u32 take = (sh_Rthr > eidx) ? (sh_Rthr - eidx) : 0u;
      if (take > 2048u) take = 2048u;
      if (take == 0u) { if (tid == 0) sh_done = 1; continue; }
      for (u32 i = tid; i < take; i += 256) key_s[i] = listE[eidx + i];
      C = take;
      if (tid == 0) sh_eidx = eidx + take;
    } else {
      u32 hloc[16];
      {
        int t0 = tid << 4;
        u32 ssum = 0;
        #pragma unroll
        for (int j = 0; j < 16; ++j) { hloc[j] = histL[t0 + j]; ssum += hloc[j]; }
        int wl = tid & 63, wid = tid >> 6;
        u32 suf = ssum;
        #pragma unroll
        for (int off = 1; off < 64; off <<= 1) {
          u32 v = __shfl_down(suf, off, 64);
          if (wl < 64 - off) suf += v;
        }
        if (wl == 0) wtot[wid] = suf;
        __syncthreads();
        u32 cross = 0;
        for (int w2 = wid + 1; w2 < 4; ++w2) cross += wtot[w2];
        u32 run = (suf - ssum) + cross;
        #pragma unroll
        for (int j = 15; j >= 0; --j) { u32 base2 = run; run += hloc[j]; histL[t0 + j] = base2; }
      }
      for (int i = tid; i < 4096; i += 256) cntArr[i] = 0;
      if (tid == 0) sh_bigF = 0;
      __syncthreads();
      #pragma unroll
      for (int r = 0; r < 20; ++r) {
        u64 k = ak[r];
        if (!k || k >= minPrev) continue;
        float s = __uint_as_float((u32)(k >> 32));
        if (digLvl >= 1) { int d0 = (int)((s - LO0) * INV0); d0 = min(max(d0, 0), 4095); if ((u32)d0 != A_B0) continue; }
        if (digLvl >= 2) { int d1 = (int)((s - lo1) * inv1); d1 = min(max(d1, 0), 4095); if ((u32)d1 != A_B1) continue; }
        if (digLvl >= 3 && ((k & kMask) != kPref)) continue;
        u32 d;
        if (digLvl == 0)      { int t0x = (int)((s - LO0) * INV0); d = (u32)min(max(t0x, 0), 4095); }
        else if (digLvl == 1) { int t1x = (int)((s - lo1) * inv1); d = (u32)min(max(t1x, 0), 4095); }
        else                  d = (u32)((k >> m1shift) & 0xFFFull);
        if (selMode == 1)      { if (d < selB) continue; }
        else if (selMode == 2) { if (d <= selB) continue; }
        u32 pos = histL[d] + atomicAdd(&cntArr[d], 1u);
        if (pos < 2048u) key_s[pos] = k;
      }
      __syncthreads();
      {
        int t0 = tid << 4;
        for (int j = 0; j < 16; ++j) {
          u32 bkt = (u32)(t0 + j);
          u32 cc = cntArr[bkt];
          if (cc >= 2u) {
            if (cc <= 48u) {
              u32 basep = histL[bkt];
              for (u32 a2 = 1; a2 < cc; ++a2) {
                u64 kv = key_s[basep + a2];
                int bi = (int)a2 - 1;
                while (bi >= 0 && key_s[basep + bi] < kv) { key_s[basep + bi + 1] = key_s[basep + bi]; --bi; }
                key_s[basep + bi + 1] = kv;
              }
            } else sh_bigF = 1;
          }
        }
      }
      __syncthreads();
      if (sh_bigF) bitonic_desc(key_s, C, tid, 256);
      if (tid == 0) sh_minPrev = key_s[C - 1];
    }
    __syncthreads();

    if (tid < 64) {
      int w = lazy_scan_g(key_s, boxes4, bbase, (int)C, wbox, outS, outB, (int)sh_w, tid);
      if (tid == 0) sh_w = (u32)w;
    }
  }

  __syncthreads();
  u32 w = sh_w;
  for (u32 p = w + (u32)tid; p < MAXT; p += 256) {
    outS[p] = -1.0f;
    *(float4*)(outB + p * 4) = make_float4(0.f, 0.f, 0.f, 0.f);
  }
}

// ---------------- final per-batch top-100: radix rank-select ----------------
__global__ __launch_bounds__(256) void merge_kernel(
    const float* __restrict__ nms_s, const float* __restrict__ nms_b,
    float* __restrict__ out_b, float* __restrict__ out_s,
    float* __restrict__ out_c, float* __restrict__ out_v)
{
  __shared__ u64 keys[NCLS * MAXT];   // 72 KB
  __shared__ u32 hist[4096];          // 16 KB
  __shared__ u64 sel[640];
  __shared__ u32 sh_cnt, sh_valid;
  __shared__ u32 sh_B, sh_incl, sh_above, sh_total;

  int b = blockIdx.x, tid = threadIdx.x;
  const int NTOT = NCLS * MAXT;

  for (int i = tid; i < NTOT; i += 256) {
    float s = nms_s[(size_t)b * NTOT + i];
    u32 u = __float_as_uint(s);
    u = (u & 0x80000000u) ? ~u : (u | 0x80000000u);
    keys[i] = ((u64)u << 32) | (u64)(0xFFFFFFFFu - (u32)i);
  }
  if (tid == 0) { sh_cnt = 0; sh_valid = 0; }

  u64 prefVal = 0;
  u64 T = 0;
  u32 need = MAXT;
  const int shifts[6] = {52, 40, 28, 16, 4, 0};
  const int widths[6] = {12, 12, 12, 12, 12, 4};
  for (int lvl = 0; lvl < 6; ++lvl) {
    int s = shifts[lvl], w = widths[lvl];
    for (int i = tid; i < 4096; i += 256) hist[i] = 0;
    __syncthreads();
    u32 dmask = (1u << w) - 1u;
    for (int i = tid; i < NTOT; i += 256) {
      u64 k = keys[i];
      if (lvl > 0 && (k >> (s + w)) != (prefVal >> (s + w))) continue;
      atomicAdd(&hist[(u32)((k >> s) & dmask)], 1u);
    }
    __syncthreads();
    if (tid < 64) {
      u32 Bx, ix, ax, tx;
      cut4096w(hist, need, tid, Bx, ix, ax, tx);
      if (tid == 0) { sh_B = Bx; sh_incl = ix; sh_above = ax; sh_total = tx; }
    }
    __syncthreads();
    u32 B = sh_B, incl = sh_incl, above = sh_above;
    if (incl <= 512u || lvl == 5) {
      T = prefVal | ((u64)B << s);
      break;
    }
    prefVal |= ((u64)B << s);
    need -= above;
  }
  __syncthreads();

  for (int i = tid; i < NTOT; i += 256) {
    u64 k = keys[i];
    if (k >= T) {
      u32 p = atomicAdd(&sh_cnt, 1u);
      if (p < 640u) sel[p] = k;
    }
  }
  __syncthreads();
  u32 cnt = sh_cnt; if (cnt > 640u) cnt = 640u;

  for (u32 j = tid; j < cnt; j += 256) {
    u64 kj = sel[j];
    u32 r = 0;
    for (u32 i = 0; i < cnt; ++i) r += (sel[i] > kj) ? 1u : 0u;
    if (r < (u32)MAXT) {
      u32 u = (u32)(kj >> 32);
      u32 bits = (u & 0x80000000u) ? (u ^ 0x80000000u) : ~u;
      float sc = __uint_as_float(bits);
      u32 flat = 0xFFFFFFFFu - (u32)(kj & 0xFFFFFFFFull);
      int cls = (int)(flat / MAXT), pos = (int)(flat % MAXT);
      out_s[b * MAXT + r] = sc;
      out_c[b * MAXT + r] = (float)(cls + 1);
      *(float4*)(out_b + ((size_t)b * MAXT + r) * 4) =
          *(const float4*)(nms_b + (((size_t)b * NCLS + cls) * MAXT + pos) * 4);
      if (sc > -1.0f) atomicAdd(&sh_valid, 1u);
    }
  }
  __syncthreads();
  if (tid == 0) out_v[b] = (float)sh_valid;
}

extern "C" void kernel_launch(void* const* d_in, const int* in_sizes, int n_in,
                              void* d_out, int out_size, void* d_ws, size_t ws_size,
                              hipStream_t stream)
{
  const float* box[5]; const float* cls[5]; const float* anc[5];
  bool interleaved = (in_sizes[1] == 2 * 57600 * 91);   // setup_inputs dict order
  if (interleaved) {
    for (int l = 0; l < 5; ++l) {
      box[l] = (const float*)d_in[3 * l + 0];
      cls[l] = (const float*)d_in[3 * l + 1];
      anc[l] = (const float*)d_in[3 * l + 2];
    }
  } else {
    for (int l = 0; l < 5; ++l) {
      box[l] = (const float*)d_in[l];
      cls[l] = (const float*)d_in[5 + l];
      anc[l] = (const float*)d_in[10 + l];
    }
  }
  const float* img = (const float*)d_in[15];

  float* ws = (float*)d_ws;
  float* boxes_ws = ws;                              // 613800 f
  u32*   cnt_pad  = (u32*)(boxes_ws + 613800);       // 180*128 u32 (8 slices x 64B stride)
  u32*   win8     = cnt_pad + 180 * 128;             // 180*8 u32
  u32*   w8cnt    = win8 + 180 * 8;                  // 180 u32
  u32*   tparams  = w8cnt + 180;                     // 4 u32 (T0, T1, panic, pad)
  u64*   listT_g  = (u64*)(tparams + 4);             // 180*8*512 u64
  float* nms_s    = (float*)(listT_g + 180 * 8 * 512); // 18000 f
  float* nms_b    = nms_s + 18000;                   // 72000 f

  const int NZ = 180 * 128;
  zero_kernel<<<(NZ + 255) / 256, 256, 0, stream>>>(cnt_pad, NZ);

  front_kernel<<<4020, 256, 0, stream>>>(
      box[0], box[1], box[2], box[3], box[4],
      anc[0], anc[1], anc[2], anc[3], anc[4],
      cls[0], cls[1], cls[2], cls[3], cls[4],
      img, boxes_ws, listT_g, cnt_pad);

  top8_kernel<<<180, 256, 0, stream>>>(listT_g, cnt_pad, boxes_ws, win8, w8cnt);

  tlb2_kernel<<<1, 256, 0, stream>>>(win8, w8cnt, tparams);

  nms_kernel<<<180, 256, 0, stream>>>(cls[0], cls[1], cls[2], cls[3], cls[4],
                                      boxes_ws, listT_g, cnt_pad, tparams, nms_s, nms_b);

  float* out_b = (float*)d_out;  // [2][100][4]
  float* out_s = out_b + 800;    // [2][100]
  float* out_c = out_s + 200;    // [2][100]
  float* out_v = out_c + 200;    // [2]
  merge_kernel<<<2, 256, 0, stream>>>(nms_s, nms_b, out_b, out_s, out_c, out_v);
}

// Round 19
// 104.674 us; speedup vs baseline: 1.2191x; 1.2191x over previous
//
#include <hip/hip_runtime.h>
#include <hip/hip_bf16.h>

typedef unsigned long long u64;
typedef unsigned int u32;

#define A_TOTAL 76725
#define NCLS 90
#define KTOP 5000u
#define MAXT 100
#define KTHR 0x3D4CCCCDu         /* bits of 0.05f */
#define TCAP 2048u               /* per-lane candidate capacity (total) */
#define SCAP 512u                /* per-slice capacity */
#define SELCAP 512u              /* fast-path >=T_b candidate cap */

__device__ __forceinline__ u64 pack_key(u32 k, u32 i) {
  return ((u64)k << 32) | (u64)(0xFFFFFFFFu - i);
}

// Full wave-0 cut with totals: B = smallest bucket with count(>=B) >= need.
__device__ __forceinline__ void cut4096w(const u32* hh, u32 need, int wl,
                                         u32& B, u32& incl, u32& above, u32& total) {
  int lo = wl << 6;
  u32 s = 0;
  #pragma unroll
  for (int j = 0; j < 64; ++j) s += hh[lo + j];
  u32 suf = s;
  #pragma unroll
  for (int off = 1; off < 64; off <<= 1) {
    u32 v = __shfl_down(suf, off, 64);
    if (wl < 64 - off) suf += v;
  }
  total = __shfl(suf, 0, 64);
  if (total < need) { B = 0; incl = total; above = 0; return; }
  u32 sufnext = suf - s;
  bool cross = (suf >= need) && (sufnext < need);
  u64 bal = __ballot(cross);
  int gl = (int)__ffsll((unsigned long long)bal) - 1;
  int glo = gl << 6;
  u32 aboveG = __shfl(sufnext, gl, 64);
  u32 hb = hh[glo + wl];
  u32 sufb = hb;
  #pragma unroll
  for (int off = 1; off < 64; off <<= 1) {
    u32 v = __shfl_down(sufb, off, 64);
    if (wl < 64 - off) sufb += v;
  }
  bool c2 = (aboveG + sufb >= need) && (aboveG + sufb - hb < need);
  u64 bal2 = __ballot(c2);
  int jB = (int)__ffsll((unsigned long long)bal2) - 1;
  B = (u32)(glo + jB);
  incl = aboveG + __shfl(sufb, jB, 64);
  above = incl - __shfl(hb, jB, 64);
}

// Block-cooperative descending bitonic sort of a[0..n) padded to pow2 with 0.
__device__ __forceinline__ void bitonic_desc(u64* a, u32 n, int tid, int nth) {
  u32 P = 2; while (P < n) P <<= 1;
  for (u32 i = tid; i < P; i += nth) if (i >= n) a[i] = 0ULL;
  __syncthreads();
  for (u32 kk = 2; kk <= P; kk <<= 1) {
    for (u32 jj = kk >> 1; jj; jj >>= 1) {
      for (u32 i = tid; i < P; i += nth) {
        u32 ixj = i ^ jj;
        if (ixj > i) {
          u64 x = a[i], y = a[ixj];
          bool up = ((i & kk) == 0);
          if (up ? (x < y) : (x > y)) { a[i] = y; a[ixj] = x; }
        }
      }
      __syncthreads();
    }
  }
}

// Wave-batch bitset greedy NMS over sorted candidates (single wave, no barriers).
__device__ __forceinline__ int bitset_scan(const u64* key_s, const float4* boxes4, size_t bbase,
                                           int C, float4* wbox, float4* bbox,
                                           float* outS, float* outB, int w, int wl) {
  int cur = 0;
  while (w < MAXT && cur < C) {
    int p = cur + wl;
    bool valid = (p < C);
    u64 kk = valid ? key_s[p] : 0ull;
    float4 mybox = make_float4(-3e30f, -3e30f, -3e30f, -3e30f);  // sentinel: zero overlap
    if (valid) {
      u32 idx = 0xFFFFFFFFu - (u32)(kk & 0xFFFFFFFFull);
      mybox = boxes4[bbase + idx];
    }
    bbox[wl] = mybox;
    float myarea = (mybox.z - mybox.x) * (mybox.w - mybox.y);
    bool alive = valid;
    for (int j = 0; j < w; ++j) {
      float4 pb = wbox[j];
      float yy1 = fmaxf(pb.x, mybox.x), xx1 = fmaxf(pb.y, mybox.y);
      float yy2 = fminf(pb.z, mybox.z), xx2 = fminf(pb.w, mybox.w);
      float inter = fmaxf(yy2 - yy1, 0.0f) * fmaxf(xx2 - xx1, 0.0f);
      bool bad = false;
      if (inter > 0.0f) {
        float pa = (pb.z - pb.x) * (pb.w - pb.y);
        bad = inter / (pa + myarea - inter + 1e-8f) > 0.3f;
      }
      alive = alive && !bad;
    }
    u64 krow = 0ull;
    int jmax = C - cur; if (jmax > 64) jmax = 64;
    for (int j = 0; j < jmax; ++j) {
      float4 pb = bbox[j];
      float yy1 = fmaxf(pb.x, mybox.x), xx1 = fmaxf(pb.y, mybox.y);
      float yy2 = fminf(pb.z, mybox.z), xx2 = fminf(pb.w, mybox.w);
      float inter = fmaxf(yy2 - yy1, 0.0f) * fmaxf(xx2 - xx1, 0.0f);
      bool kill = false;
      if (inter > 0.0f) {
        float pa = (pb.z - pb.x) * (pb.w - pb.y);
        kill = inter / (pa + myarea - inter + 1e-8f) > 0.3f;
      }
      if (kill) krow |= (1ull << j);
    }
    u32 krlo = (u32)krow, krhi = (u32)(krow >> 32);
    u64 amask = __ballot(alive);
    int myord = -1;
    while (amask != 0ull && w < MAXT) {
      int js = (int)__ffsll((unsigned long long)amask) - 1;
      u32 klo = __shfl(krlo, js, 64);
      u32 khi = __shfl(krhi, js, 64);
      u64 kr = ((u64)khi << 32) | (u64)klo;
      if (wl == js) myord = w;
      amask &= ~kr;
      amask &= ~(1ull << js);
      w++;
    }
    if (myord >= 0) {
      outS[myord] = __uint_as_float((u32)(kk >> 32));
      *(float4*)(outB + myord * 4) = mybox;
      wbox[myord] = mybox;
    }
    cur += 64;
  }
  return w;
}

// Wave-level lazy greedy NMS (fallback tier only; original semantics).
__device__ __forceinline__ int lazy_scan_g(const u64* key_s, const float4* boxes4, size_t bbase,
                                           int C, float4* wbox, float* outS, float* outB,
                                           int w, int wl) {
  int cur = 0;
  while (w < MAXT && cur < C) {
    int p = cur + wl;
    bool alive = (p < C);
    u64 kk = alive ? key_s[p] : 0ull;
    float4 mybox = make_float4(0.f, 0.f, 0.f, 0.f);
    if (alive) {
      u32 idx = 0xFFFFFFFFu - (u32)(kk & 0xFFFFFFFFull);
      mybox = boxes4[bbase + idx];
    }
    float myarea = (mybox.z - mybox.x) * (mybox.w - mybox.y);
    for (int j = 0; j < w; ++j) {
      float4 pb = wbox[j];
      float yy1 = fmaxf(pb.x, mybox.x), xx1 = fmaxf(pb.y, mybox.y);
      float yy2 = fminf(pb.z, mybox.z), xx2 = fminf(pb.w, mybox.w);
      float inter = fmaxf(yy2 - yy1, 0.0f) * fmaxf(xx2 - xx1, 0.0f);
      bool bad = false;
      if (inter > 0.0f) {
        float pa = (pb.z - pb.x) * (pb.w - pb.y);
        bad = inter / (pa + myarea - inter + 1e-8f) > 0.3f;
      }
      alive = alive && !bad;
    }
    for (;;) {
      u64 bal = __ballot(alive);
      if (bal == 0ull) break;
      int js = (int)__ffsll((unsigned long long)bal) - 1;
      float4 pb;
      pb.x = __shfl(mybox.x, js, 64);
      pb.y = __shfl(mybox.y, js, 64);
      pb.z = __shfl(mybox.z, js, 64);
      pb.w = __shfl(mybox.w, js, 64);
      u64 wk = __shfl(kk, js, 64);
      if (wl == 0) {
        outS[w] = __uint_as_float((u32)(wk >> 32));
        *(float4*)(outB + w * 4) = pb;
        wbox[w] = pb;
      }
      w++;
      if (w >= MAXT) break;
      if (wl <= js) alive = false;
      else if (alive) {
        float yy1 = fmaxf(pb.x, mybox.x), xx1 = fmaxf(pb.y, mybox.y);
        float yy2 = fminf(pb.z, mybox.z), xx2 = fminf(pb.w, mybox.w);
        float inter = fmaxf(yy2 - yy1, 0.0f) * fmaxf(xx2 - xx1, 0.0f);
        if (inter > 0.0f) {
          float pa = (pb.z - pb.x) * (pb.w - pb.y);
          if (inter / (pa + myarea - inter + 1e-8f) > 0.3f) alive = false;
        }
      }
    }
    cur += 64;
  }
  return w;
}

// ---------------- workspace zeroing ----------------
__global__ __launch_bounds__(256) void zero_kernel(u32* __restrict__ p, int n) {
  int i = blockIdx.x * 256 + threadIdx.x;
  if (i < n) p[i] = 0;
}

// ---------------- fused decode+clip (blocks 0..599) and streaming collect (600..4019) ----------------
__device__ __forceinline__ void coll_elem(int i, float x, int b, int base, int slice,
                                          u64* __restrict__ listT_g, u32* __restrict__ cnt_pad) {
  if (x >= 0.0f) {                  // s >= 0.5
    u32 a = (u32)i / 91u;           // compile-time magic-mul
    u32 c = (u32)i - a * 91u;
    if (c != 0u) {
      float s = 1.0f / (1.0f + expf(-x));
      int lane = b * NCLS + (int)c - 1;
      u32 idx = (u32)base + a;
      u32 p = atomicAdd(&cnt_pad[lane * 128 + slice * 16], 1u);
      if (p < SCAP) listT_g[(((size_t)lane * 8 + slice) << 9) + p] = pack_key(__float_as_uint(s), idx);
    }
  }
}

__global__ __launch_bounds__(256) void front_kernel(
    const float* __restrict__ bx0, const float* __restrict__ bx1, const float* __restrict__ bx2,
    const float* __restrict__ bx3, const float* __restrict__ bx4,
    const float* __restrict__ an0, const float* __restrict__ an1, const float* __restrict__ an2,
    const float* __restrict__ an3, const float* __restrict__ an4,
    const float* __restrict__ c3, const float* __restrict__ c4, const float* __restrict__ c5,
    const float* __restrict__ c6, const float* __restrict__ c7,
    const float* __restrict__ img, float* __restrict__ boxes,
    u64* __restrict__ listT_g, u32* __restrict__ cnt_pad)
{
  int blk = blockIdx.x, tid = threadIdx.x;
  if (blk < 600) {
    int t = blk * 256 + tid;
    if (t >= 2 * A_TOTAL) return;
    int b = t / A_TOTAL, a = t % A_TOTAL;
    const float* bp; const float* ap; int al; int nl;
    if (a < 57600)      { bp = bx0; ap = an0; al = a;          nl = 57600; }
    else if (a < 72000) { bp = bx1; ap = an1; al = a - 57600;  nl = 14400; }
    else if (a < 75600) { bp = bx2; ap = an2; al = a - 72000;  nl = 3600;  }
    else if (a < 76500) { bp = bx3; ap = an3; al = a - 75600;  nl = 900;   }
    else                { bp = bx4; ap = an4; al = a - 76500;  nl = 225;   }
    float4 e  = *(const float4*)(bp + ((size_t)b * nl + al) * 4);
    float4 an = *(const float4*)(ap + ((size_t)b * nl + al) * 4);
    const float CLIP = 4.135166556742356f; // log(1000/16)
    float ah  = an.z - an.x + 1.0f;
    float aw  = an.w - an.y + 1.0f;
    float ayc = an.x + 0.5f * ah;
    float axc = an.y + 0.5f * aw;
    float dh = fminf(e.z, CLIP), dw = fminf(e.w, CLIP);
    float yc = e.x * ah + ayc;
    float xc = e.y * aw + axc;
    float h  = expf(dh) * ah;
    float w  = expf(dw) * aw;
    float ymin = yc - 0.5f * h;
    float xmin = xc - 0.5f * w;
    float ymax = ymin + h - 1.0f;
    float xmax = xmin + w - 1.0f;
    float H = img[b * 2 + 0], W = img[b * 2 + 1];
    float4 o;
    o.x = fminf(fmaxf(ymin, 0.0f), H);
    o.y = fminf(fmaxf(xmin, 0.0f), W);
    o.z = fminf(fmaxf(ymax, 0.0f), H);
    o.w = fminf(fmaxf(xmax, 0.0f), W);
    *(float4*)(boxes + (size_t)t * 4) = o;
    return;
  }
  int blk2 = blk - 600;
  int slice = blk2 & 7;
  const float* cls; int n, base, b, loc, J, lvl;
  if (blk2 < 2560)      { lvl = 0; cls = c3; n = 57600; base = 0;     J = 1280; int r = blk2;        b = r >= J; loc = b ? r - J : r; }
  else if (blk2 < 3200) { lvl = 1; cls = c4; n = 14400; base = 57600; J = 320;  int r = blk2 - 2560; b = r >= J; loc = b ? r - J : r; }
  else if (blk2 < 3360) { lvl = 2; cls = c5; n = 3600;  base = 72000; J = 80;   int r = blk2 - 3200; b = r >= J; loc = b ? r - J : r; }
  else if (blk2 < 3400) { lvl = 3; cls = c6; n = 900;   base = 75600; J = 20;   int r = blk2 - 3360; b = r >= J; loc = b ? r - J : r; }
  else                  { lvl = 4; cls = c7; n = 225;   base = 76500; J = 10;   int r = blk2 - 3400; b = r >= J; loc = b ? r - J : r; }

  if (lvl <= 3) {
    int F4 = n * 91 / 4;
    int chunk = (F4 + J - 1) / J;
    int q0 = loc * chunk;
    int q1 = q0 + chunk; if (q1 > F4) q1 = F4;
    const float4* src4 = (const float4*)(cls + (size_t)b * n * 91);
    for (int q = q0 + tid; q < q1; q += 256) {
      float4 v = src4[q];
      int i0 = q << 2;
      coll_elem(i0,     v.x, b, base, slice, listT_g, cnt_pad);
      coll_elem(i0 + 1, v.y, b, base, slice, listT_g, cnt_pad);
      coll_elem(i0 + 2, v.z, b, base, slice, listT_g, cnt_pad);
      coll_elem(i0 + 3, v.w, b, base, slice, listT_g, cnt_pad);
    }
  } else {
    int F = n * 91;                 // 20475 (not /4-divisible) -> scalar
    int chunk = (F + J - 1) / J;
    int s0 = loc * chunk;
    int s1 = s0 + chunk; if (s1 > F) s1 = F;
    const float* src = cls + (size_t)b * F;
    for (int i = s0 + tid; i < s1; i += 256) coll_elem(i, src[i], b, base, slice, listT_g, cnt_pad);
  }
}

// ---------------- phase 1: per-lane top-8 prefix greedy -> true winner subset ----------------
__global__ __launch_bounds__(256) void top8_kernel(
    const u64* __restrict__ listT_g, const u32* __restrict__ cnt_pad,
    const float* __restrict__ boxes, u32* __restrict__ win8, u32* __restrict__ w8cnt)
{
  __shared__ u64 wred[4];
  __shared__ u64 sh_top;
  __shared__ u64 topk[8];
  __shared__ float4 tb[8];
  int tid = threadIdx.x;
  int lane = blockIdx.x;

  u32 pre[9]; pre[0] = 0;
  bool of = false;
  #pragma unroll
  for (int j = 0; j < 8; ++j) {
    u32 cj = cnt_pad[lane * 128 + j * 16];
    of |= (cj > SCAP);
    pre[j + 1] = pre[j] + cj;
  }
  u32 cnt = pre[8];
  if (of || cnt > TCAP) { if (tid == 0) w8cnt[lane] = 0xFFFFu; return; }

  u64 kr[8];
  #pragma unroll
  for (int r = 0; r < 8; ++r) {
    u32 s = (u32)tid + (u32)r * 256u;
    u64 k = 0ull;
    if (s < cnt) {
      u32 j = 0;
      #pragma unroll
      for (int t = 1; t < 8; ++t) if (s >= pre[t]) j = (u32)t;
      k = listT_g[(((size_t)lane * 8 + j) << 9) + (s - pre[j])];
    }
    kr[r] = k;
  }

  int nt = 0;
  for (int it = 0; it < 8; ++it) {
    u64 m = kr[0];
    #pragma unroll
    for (int r = 1; r < 8; ++r) if (kr[r] > m) m = kr[r];
    #pragma unroll
    for (int off = 1; off < 64; off <<= 1) {
      u64 o = __shfl_xor(m, off);
      if (o > m) m = o;
    }
    if ((tid & 63) == 0) wred[tid >> 6] = m;
    __syncthreads();
    if (tid == 0) {
      u64 w = wred[0];
      if (wred[1] > w) w = wred[1];
      if (wred[2] > w) w = wred[2];
      if (wred[3] > w) w = wred[3];
      sh_top = w;
      topk[it] = w;
    }
    __syncthreads();
    u64 ch = sh_top;
    if (ch == 0ull) break;
    #pragma unroll
    for (int r = 0; r < 8; ++r) if (kr[r] == ch) kr[r] = 0ull;   // keys unique
    nt = it + 1;
  }
  __syncthreads();
  const float4* boxes4 = (const float4*)boxes;
  size_t bbase = (size_t)(lane / NCLS) * A_TOTAL;
  if (tid < nt) {
    u32 idx = 0xFFFFFFFFu - (u32)(topk[tid] & 0xFFFFFFFFull);
    tb[tid] = boxes4[bbase + idx];
  }
  __syncthreads();
  if (tid == 0) {
    float4 abox[8];
    int w8 = 0;
    for (int i = 0; i < nt; ++i) {
      float4 mb = tb[i];
      float ma = (mb.z - mb.x) * (mb.w - mb.y);
      bool alive = true;
      for (int j = 0; j < w8; ++j) {
        float4 pb = abox[j];
        float yy1 = fmaxf(pb.x, mb.x), xx1 = fmaxf(pb.y, mb.y);
        float yy2 = fminf(pb.z, mb.z), xx2 = fminf(pb.w, mb.w);
        float inter = fmaxf(yy2 - yy1, 0.0f) * fmaxf(xx2 - xx1, 0.0f);
        if (inter > 0.0f) {
          float pa = (pb.z - pb.x) * (pb.w - pb.y);
          if (inter / (pa + ma - inter + 1e-8f) > 0.3f) alive = false;
        }
      }
      if (alive) {
        win8[lane * 8 + w8] = (u32)(topk[i] >> 32);
        abox[w8] = mb;
        w8++;
      }
    }
    w8cnt[lane] = (u32)w8;
  }
}

// ---------------- phase 2: per-batch T_b lower bound via 4096-bucket histogram ----------------
// T_b = lower edge of the bucket containing the 100th-largest subset winner.
// Any lower bound on that value is a SAFE prune threshold.
__global__ __launch_bounds__(256) void tlb2_kernel(const u32* __restrict__ win8,
                                                   const u32* __restrict__ w8cnt,
                                                   u32* __restrict__ tparams)
{
  __shared__ u32 hist[4096];
  __shared__ u32 sh_tot, sh_panic;
  __shared__ u32 sh_B, sh_total;
  int t = threadIdx.x;
  if (t == 0) sh_panic = 0;
  __syncthreads();
  for (int b = 0; b < 2; ++b) {
    for (int i = t; i < 4096; i += 256) hist[i] = 0;
    if (t == 0) sh_tot = 0;
    __syncthreads();
    u32 mycnt = 0;
    for (int i = t; i < 720; i += 256) {
      int ln = b * NCLS + i / 8;
      u32 cc = w8cnt[ln];
      if (cc == 0xFFFFu) { sh_panic = 1; }
      else if ((u32)(i & 7) < cc) {
        u32 v = win8[ln * 8 + (i & 7)];
        atomicAdd(&hist[v >> 19], 1u);
        mycnt++;
      }
    }
    atomicAdd(&sh_tot, mycnt);
    __syncthreads();
    if (t < 64) {
      u32 Bx, ix, ax, tx;
      cut4096w(hist, 100u, t, Bx, ix, ax, tx);
      if (t == 0) { sh_B = Bx; sh_total = tx; }
    }
    __syncthreads();
    if (t == 0) {
      tparams[b] = sh_B << 19;               // lower bound on 100th-largest winner score bits
      if (sh_tot < 100u || sh_total < 100u) sh_panic = 1;
    }
    __syncthreads();
  }
  if (t == 0) tparams[2] = sh_panic;
}

// ---------------- per-lane NMS: T_b fast path + exact in-kernel fallback ----------------
__global__ __launch_bounds__(256) void nms_kernel(
    const float* __restrict__ c3, const float* __restrict__ c4, const float* __restrict__ c5,
    const float* __restrict__ c6, const float* __restrict__ c7,
    const float* __restrict__ boxes, const u64* __restrict__ listT_g,
    const u32* __restrict__ cnt_pad, const u32* __restrict__ tparams,
    float* __restrict__ nms_s, float* __restrict__ nms_b)
{
  __shared__ __align__(16) char big[40960];     // fallback: listA u64[5120] -> cntArr u32[4096]
  __shared__ __align__(16) u64 listE[2048];     // fallback only
  __shared__ u64 key_s[2048];
  __shared__ __align__(16) u32 histL[4096];     // fallback hist; fast path: sel u64[SELCAP]
  __shared__ float4 wbox[MAXT];
  __shared__ float4 bbox[64];
  __shared__ u32 wtot[4];
  __shared__ u32 sh_flag, sh_cS;
  __shared__ u64 sh_minPrev;
  __shared__ u32 sh_w, sh_done, sh_eidx, sh_Rthr, sh_eSorted, sh_bigF;
  __shared__ u32 sh_B, sh_incl, sh_above, sh_total, sh_cA, sh_cE, sh_B2;

  int tid = threadIdx.x;
  int lane = blockIdx.x;
  int b = lane / NCLS, c = lane % NCLS;
  const float4* boxes4 = (const float4*)boxes;
  size_t bbase = (size_t)b * A_TOTAL;
  const u64 thrpack = ((u64)KTHR) << 32;

  float* outS = nms_s + (size_t)lane * MAXT;
  float* outB = nms_b + (size_t)lane * MAXT * 4;

  u32 pre[9]; pre[0] = 0;
  bool of = false;
  #pragma unroll
  for (int j = 0; j < 8; ++j) {
    u32 cj = cnt_pad[lane * 128 + j * 16];
    of |= (cj > SCAP);
    pre[j + 1] = pre[j] + cj;
  }
  u32 cnt = pre[8];
  u32 Tlb = tparams[b], panic = tparams[2];
  if (tid == 0) { sh_flag = (of || cnt > TCAP || panic) ? 1u : 0u; sh_cS = 0; }
  __syncthreads();

  if (!sh_flag) {
    // fast path: only candidates >= T_b can reach the final per-batch top-100
    const u64 Tpack = ((u64)Tlb) << 32;
    u64* sel = (u64*)histL;
    #pragma unroll
    for (int r = 0; r < 8; ++r) {
      u32 s = (u32)tid + (u32)r * 256u;
      if (s < cnt) {
        u32 j = 0;
        #pragma unroll
        for (int t = 1; t < 8; ++t) if (s >= pre[t]) j = (u32)t;
        u64 k = listT_g[(((size_t)lane * 8 + j) << 9) + (s - pre[j])];
        if (k >= Tpack) {
          u32 p = atomicAdd(&sh_cS, 1u);
          if (p < SELCAP) sel[p] = k;
        }
      }
    }
    __syncthreads();
    u32 Cs = sh_cS;
    if (Cs > SELCAP) {
      if (tid == 0) sh_flag = 1;
    } else {
      for (u32 j = tid; j < Cs; j += 256) {
        u64 kj = sel[j];
        u32 rk = 0;
        for (u32 i2 = 0; i2 < Cs; ++i2) rk += (sel[i2] > kj) ? 1u : 0u;
        key_s[rk] = kj;
      }
      __syncthreads();
      if (tid < 64) {
        int w = bitset_scan(key_s, boxes4, bbase, (int)Cs, wbox, bbox, outS, outB, 0, tid);
        if (tid == 0) sh_w = (u32)w;     // w < MAXT expected: rest provably below final top-100
      }
    }
  }
  __syncthreads();
  if (!sh_flag) {
    u32 w = sh_w;
    for (u32 p = w + (u32)tid; p < MAXT; p += 256) {
      outS[p] = -1.0f;
      *(float4*)(outB + p * 4) = make_float4(0.f, 0.f, 0.f, 0.f);
    }
    return;
  }

  // ================= EXACT FALLBACK (rare): rebuild from raw column =================
  auto sb_of = [&](int i) -> u32 {
    const float* p; int al, nl;
    if (i < 57600)      { p = c3; al = i;          nl = 57600; }
    else if (i < 72000) { p = c4; al = i - 57600;  nl = 14400; }
    else if (i < 75600) { p = c5; al = i - 72000;  nl = 3600;  }
    else if (i < 76500) { p = c6; al = i - 75600;  nl = 900;   }
    else                { p = c7; al = i - 76500;  nl = 225;   }
    float x = p[((size_t)b * nl + al) * 91 + (c + 1)];
    float s = 1.0f / (1.0f + expf(-x));
    return __float_as_uint(s);
  };

  u64* listA = (u64*)big;
  for (int i = tid; i < 4096; i += 256) histL[i] = 0;
  if (tid == 0) {
    sh_cA = 0; sh_cE = 0; sh_w = 0; sh_done = 0; sh_eidx = 0; sh_eSorted = 0; sh_minPrev = ~0ull;
  }
  __syncthreads();
  for (int i = tid; i < A_TOTAL; i += 256) atomicAdd(&histL[sb_of(i) >> 19], 1u);
  __syncthreads();
  if (tid < 64) {
    u32 Bx, ix, ax, tx;
    cut4096w(histL, KTOP, tid, Bx, ix, ax, tx);
    if (tid == 0) sh_B = Bx;
  }
  __syncthreads();
  u32 B = sh_B;
  for (int i = tid; i < A_TOTAL; i += 256) {
    u32 u = sb_of(i);
    u32 bkt = u >> 19;
    if (bkt > B) {
      u32 p = atomicAdd(&sh_cA, 1u);
      if (p < 5120u) listA[p] = pack_key(u, (u32)i);
    } else if (bkt == B) {
      u32 p = atomicAdd(&sh_cE, 1u);
      if (p < 2048u) listE[p] = pack_key(u, (u32)i);
    }
  }
  __syncthreads();
  u32 g = sh_cA, h = sh_cE;
  if (h > 2048u) {
    for (int i = tid; i < 4096; i += 256) histL[i] = 0;
    if (tid == 0) sh_cE = 0;
    __syncthreads();
    for (int i = tid; i < A_TOTAL; i += 256) {
      u32 u = sb_of(i);
      if ((u >> 19) == B) atomicAdd(&histL[(u >> 7) & 0xFFFu], 1u);
    }
    __syncthreads();
    u32 R1 = KTOP - g;
    if (tid < 64) {
      u32 Bx, ix, ax, tx;
      cut4096w(histL, R1, tid, Bx, ix, ax, tx);
      if (tid == 0) sh_B2 = Bx;
    }
    __syncthreads();
    u32 B2 = sh_B2;
    for (int i = tid; i < A_TOTAL; i += 256) {
      u32 u = sb_of(i);
      if ((u >> 19) == B) {
        u32 sb2 = (u >> 7) & 0xFFFu;
        if (sb2 > B2) {
          u32 p = atomicAdd(&sh_cA, 1u);
          if (p < 5120u) listA[p] = pack_key(u, (u32)i);
        } else if (sb2 == B2) {
          u32 p = atomicAdd(&sh_cE, 1u);
          if (p < 2048u) listE[p] = pack_key(u, (u32)i);
        }
      }
    }
    __syncthreads();
    g = sh_cA; h = sh_cE; if (h > 2048u) h = 2048u;
  }
  if (g > 5120u) g = 5120u;
  u32 R = (g < KTOP) ? (KTOP - g) : 0u; if (R > h) R = h;

  u64 ak[20];
  #pragma unroll
  for (int r = 0; r < 20; ++r) {
    u32 s2 = (u32)tid + (u32)r * 256u;
    u64 kp = (s2 < g) ? listA[s2] : 0ull;
    if (kp < thrpack) kp = 0ull;
    ak[r] = kp;
  }
  __syncthreads();
  u32* cntArr = (u32*)big;

  const float LO0  = 0.04f;
  const float INV0 = 4096.0f / (1.001f - 0.04f);

  for (int seg = 0; seg < 7200; ++seg) {
    __syncthreads();
    if (sh_w >= MAXT || sh_done) break;
    u64 minPrev = sh_minPrev;

    int digLvl = 0;
    u32 A_B0 = 0, A_B1 = 0;
    float lo1 = 0.f, inv1 = 0.f;
    u64 kMask = 0, kPref = 0;
    int m1shift = 32;
    int selMode = -1;
    u32 selB = 0;
    u32 C = 0;
    bool fromE = false;

    for (int lvl = 0; lvl < 8; ++lvl) {
      for (int i = tid; i < 4096; i += 256) histL[i] = 0;
      __syncthreads();
      #pragma unroll
      for (int r = 0; r < 20; ++r) {
        u64 k = ak[r];
        if (!k || k >= minPrev) continue;
        float s = __uint_as_float((u32)(k >> 32));
        if (digLvl >= 1) { int d0 = (int)((s - LO0) * INV0); d0 = min(max(d0, 0), 4095); if ((u32)d0 != A_B0) continue; }
        if (digLvl >= 2) { int d1 = (int)((s - lo1) * inv1); d1 = min(max(d1, 0), 4095); if ((u32)d1 != A_B1) continue; }
        if (digLvl >= 3 && ((k & kMask) != kPref)) continue;
        u32 d;
        if (digLvl == 0)      { int t0 = (int)((s - LO0) * INV0); d = (u32)min(max(t0, 0), 4095); }
        else if (digLvl == 1) { int t1 = (int)((s - lo1) * inv1); d = (u32)min(max(t1, 0), 4095); }
        else                  d = (u32)((k >> m1shift) & 0xFFFull);
        atomicAdd(&histL[d], 1u);
      }
      __syncthreads();
      if (tid < 64) {
        u32 Bx, ix, ax, tx;
        cut4096w(histL, 1024u, tid, Bx, ix, ax, tx);
        if (tid == 0) { sh_B = Bx; sh_incl = ix; sh_above = ax; sh_total = tx; }
      }
      __syncthreads();
      u32 total = sh_total, incl = sh_incl, above = sh_above, Bx = sh_B;
      if (total == 0u)   { fromE = true; break; }
      if (total < 1024u) { selMode = 0; C = total; break; }
      if (incl <= 2048u) { selMode = 1; selB = Bx; C = incl; break; }
      if (above > 0u)    { selMode = 2; selB = Bx; C = above; break; }
      if (digLvl == 0) {
        A_B0 = Bx;
        lo1 = LO0 + (float)Bx / INV0;
        inv1 = INV0 * 4096.0f;
        digLvl = 1;
      } else if (digLvl == 1) {
        A_B1 = Bx;
        digLvl = 2; m1shift = 32;
      } else {
        kPref |= ((u64)Bx << m1shift);
        kMask |= (0xFFFull << m1shift);
        m1shift -= 12;
        digLvl++;
      }
      __syncthreads();
    }

    if (fromE) {
      if (!sh_eSorted) {
        bitonic_desc(listE, h, tid, 256);
        if (tid == 0) {
          u32 lo = 0, hi2 = h;
          while (lo < hi2) { u32 mid = (lo + hi2) >> 1; if (listE[mid] >= thrpack) lo = mid + 1; else hi2 = mid; }
          sh_Rthr = (R < lo) ? R : lo;
          sh_eSorted = 1;
        }
        __syncthreads();
      }
      u32 eidx = sh_eidx;
      u32 take = (sh_Rthr > eidx) ? (sh_Rthr - eidx) : 0u;
      if (take > 2048u) take = 2048u;
      if (take == 0u) { if (tid == 0) sh_done = 1; continue; }
      for (u32 i = tid; i < take; i += 256) key_s[i] = listE[eidx + i];
      C = take;
      if (tid == 0) sh_eidx = eidx + take;
    } else {
      u32 hloc[16];
      {
        int t0 = tid << 4;
        u32 ssum = 0;
        #pragma unroll
        for (int j = 0; j < 16; ++j) { hloc[j] = histL[t0 + j]; ssum += hloc[j]; }
        int wl = tid & 63, wid = tid >> 6;
        u32 suf = ssum;
        #pragma unroll
        for (int off = 1; off < 64; off <<= 1) {
          u32 v = __shfl_down(suf, off, 64);
          if (wl < 64 - off) suf += v;
        }
        if (wl == 0) wtot[wid] = suf;
        __syncthreads();
        u32 cross = 0;
        for (int w2 = wid + 1; w2 < 4; ++w2) cross += wtot[w2];
        u32 run = (suf - ssum) + cross;
        #pragma unroll
        for (int j = 15; j >= 0; --j) { u32 base2 = run; run += hloc[j]; histL[t0 + j] = base2; }
      }
      for (int i = tid; i < 4096; i += 256) cntArr[i] = 0;
      if (tid == 0) sh_bigF = 0;
      __syncthreads();
      #pragma unroll
      for (int r = 0; r < 20; ++r) {
        u64 k = ak[r];
        if (!k || k >= minPrev) continue;
        float s = __uint_as_float((u32)(k >> 32));
        if (digLvl >= 1) { int d0 = (int)((s - LO0) * INV0); d0 = min(max(d0, 0), 4095); if ((u32)d0 != A_B0) continue; }
        if (digLvl >= 2) { int d1 = (int)((s - lo1) * inv1); d1 = min(max(d1, 0), 4095); if ((u32)d1 != A_B1) continue; }
        if (digLvl >= 3 && ((k & kMask) != kPref)) continue;
        u32 d;
        if (digLvl == 0)      { int t0x = (int)((s - LO0) * INV0); d = (u32)min(max(t0x, 0), 4095); }
        else if (digLvl == 1) { int t1x = (int)((s - lo1) * inv1); d = (u32)min(max(t1x, 0), 4095); }
        else                  d = (u32)((k >> m1shift) & 0xFFFull);
        if (selMode == 1)      { if (d < selB) continue; }
        else if (selMode == 2) { if (d <= selB) continue; }
        u32 pos = histL[d] + atomicAdd(&cntArr[d], 1u);
        if (pos < 2048u) key_s[pos] = k;
      }
      __syncthreads();
      {
        int t0 = tid << 4;
        for (int j = 0; j < 16; ++j) {
          u32 bkt = (u32)(t0 + j);
          u32 cc = cntArr[bkt];
          if (cc >= 2u) {
            if (cc <= 48u) {
              u32 basep = histL[bkt];
              for (u32 a2 = 1; a2 < cc; ++a2) {
                u64 kv = key_s[basep + a2];
                int bi = (int)a2 - 1;
                while (bi >= 0 && key_s[basep + bi] < kv) { key_s[basep + bi + 1] = key_s[basep + bi]; --bi; }
                key_s[basep + bi + 1] = kv;
              }
            } else sh_bigF = 1;
          }
        }
      }
      __syncthreads();
      if (sh_bigF) bitonic_desc(key_s, C, tid, 256);
      if (tid == 0) sh_minPrev = key_s[C - 1];
    }
    __syncthreads();

    if (tid < 64) {
      int w = lazy_scan_g(key_s, boxes4, bbase, (int)C, wbox, outS, outB, (int)sh_w, tid);
      if (tid == 0) sh_w = (u32)w;
    }
  }

  __syncthreads();
  u32 w = sh_w;
  for (u32 p = w + (u32)tid; p < MAXT; p += 256) {
    outS[p] = -1.0f;
    *(float4*)(outB + p * 4) = make_float4(0.f, 0.f, 0.f, 0.f);
  }
}

// ---------------- final per-batch top-100: radix rank-select ----------------
__global__ __launch_bounds__(256) void merge_kernel(
    const float* __restrict__ nms_s, const float* __restrict__ nms_b,
    float* __restrict__ out_b, float* __restrict__ out_s,
    float* __restrict__ out_c, float* __restrict__ out_v)
{
  __shared__ u64 keys[NCLS * MAXT];   // 72 KB
  __shared__ u32 hist[4096];          // 16 KB
  __shared__ u64 sel[640];
  __shared__ u32 sh_cnt, sh_valid;
  __shared__ u32 sh_B, sh_incl, sh_above, sh_total;

  int b = blockIdx.x, tid = threadIdx.x;
  const int NTOT = NCLS * MAXT;

  for (int i = tid; i < NTOT; i += 256) {
    float s = nms_s[(size_t)b * NTOT + i];
    u32 u = __float_as_uint(s);
    u = (u & 0x80000000u) ? ~u : (u | 0x80000000u);
    keys[i] = ((u64)u << 32) | (u64)(0xFFFFFFFFu - (u32)i);
  }
  if (tid == 0) { sh_cnt = 0; sh_valid = 0; }

  u64 prefVal = 0;
  u64 T = 0;
  u32 need = MAXT;
  const int shifts[6] = {52, 40, 28, 16, 4, 0};
  const int widths[6] = {12, 12, 12, 12, 12, 4};
  for (int lvl = 0; lvl < 6; ++lvl) {
    int s = shifts[lvl], w = widths[lvl];
    for (int i = tid; i < 4096; i += 256) hist[i] = 0;
    __syncthreads();
    u32 dmask = (1u << w) - 1u;
    for (int i = tid; i < NTOT; i += 256) {
      u64 k = keys[i];
      if (lvl > 0 && (k >> (s + w)) != (prefVal >> (s + w))) continue;
      atomicAdd(&hist[(u32)((k >> s) & dmask)], 1u);
    }
    __syncthreads();
    if (tid < 64) {
      u32 Bx, ix, ax, tx;
      cut4096w(hist, need, tid, Bx, ix, ax, tx);
      if (tid == 0) { sh_B = Bx; sh_incl = ix; sh_above = ax; sh_total = tx; }
    }
    __syncthreads();
    u32 B = sh_B, incl = sh_incl, above = sh_above;
    if (incl <= 512u || lvl == 5) {
      T = prefVal | ((u64)B << s);
      break;
    }
    prefVal |= ((u64)B << s);
    need -= above;
  }
  __syncthreads();

  for (int i = tid; i < NTOT; i += 256) {
    u64 k = keys[i];
    if (k >= T) {
      u32 p = atomicAdd(&sh_cnt, 1u);
      if (p < 640u) sel[p] = k;
    }
  }
  __syncthreads();
  u32 cnt = sh_cnt; if (cnt > 640u) cnt = 640u;

  for (u32 j = tid; j < cnt; j += 256) {
    u64 kj = sel[j];
    u32 r = 0;
    for (u32 i = 0; i < cnt; ++i) r += (sel[i] > kj) ? 1u : 0u;
    if (r < (u32)MAXT) {
      u32 u = (u32)(kj >> 32);
      u32 bits = (u & 0x80000000u) ? (u ^ 0x80000000u) : ~u;
      float sc = __uint_as_float(bits);
      u32 flat = 0xFFFFFFFFu - (u32)(kj & 0xFFFFFFFFull);
      int cls = (int)(flat / MAXT), pos = (int)(flat % MAXT);
      out_s[b * MAXT + r] = sc;
      out_c[b * MAXT + r] = (float)(cls + 1);
      *(float4*)(out_b + ((size_t)b * MAXT + r) * 4) =
          *(const float4*)(nms_b + (((size_t)b * NCLS + cls) * MAXT + pos) * 4);
      if (sc > -1.0f) atomicAdd(&sh_valid, 1u);
    }
  }
  __syncthreads();
  if (tid == 0) out_v[b] = (float)sh_valid;
}

extern "C" void kernel_launch(void* const* d_in, const int* in_sizes, int n_in,
                              void* d_out, int out_size, void* d_ws, size_t ws_size,
                              hipStream_t stream)
{
  const float* box[5]; const float* cls[5]; const float* anc[5];
  bool interleaved = (in_sizes[1] == 2 * 57600 * 91);   // setup_inputs dict order
  if (interleaved) {
    for (int l = 0; l < 5; ++l) {
      box[l] = (const float*)d_in[3 * l + 0];
      cls[l] = (const float*)d_in[3 * l + 1];
      anc[l] = (const float*)d_in[3 * l + 2];
    }
  } else {
    for (int l = 0; l < 5; ++l) {
      box[l] = (const float*)d_in[l];
      cls[l] = (const float*)d_in[5 + l];
      anc[l] = (const float*)d_in[10 + l];
    }
  }
  const float* img = (const float*)d_in[15];

  float* ws = (float*)d_ws;
  float* boxes_ws = ws;                              // 613800 f
  u32*   cnt_pad  = (u32*)(boxes_ws + 613800);       // 180*128 u32 (8 slices x 64B stride)
  u32*   win8     = cnt_pad + 180 * 128;             // 180*8 u32
  u32*   w8cnt    = win8 + 180 * 8;                  // 180 u32
  u32*   tparams  = w8cnt + 180;                     // 4 u32 (T0, T1, panic, pad)
  u64*   listT_g  = (u64*)(tparams + 4);             // 180*8*512 u64
  float* nms_s    = (float*)(listT_g + 180 * 8 * 512); // 18000 f
  float* nms_b    = nms_s + 18000;                   // 72000 f

  const int NZ = 180 * 128;
  zero_kernel<<<(NZ + 255) / 256, 256, 0, stream>>>(cnt_pad, NZ);

  front_kernel<<<4020, 256, 0, stream>>>(
      box[0], box[1], box[2], box[3], box[4],
      anc[0], anc[1], anc[2], anc[3], anc[4],
      cls[0], cls[1], cls[2], cls[3], cls[4],
      img, boxes_ws, listT_g, cnt_pad);

  top8_kernel<<<180, 256, 0, stream>>>(listT_g, cnt_pad, boxes_ws, win8, w8cnt);

  tlb2_kernel<<<1, 256, 0, stream>>>(win8, w8cnt, tparams);

  nms_kernel<<<180, 256, 0, stream>>>(cls[0], cls[1], cls[2], cls[3], cls[4],
                                      boxes_ws, listT_g, cnt_pad, tparams, nms_s, nms_b);

  float* out_b = (float*)d_out;  // [2][100][4]
  float* out_s = out_b + 800;    // [2][100]
  float* out_c = out_s + 200;    // [2][100]
  float* out_v = out_c + 200;    // [2]
  merge_kernel<<<2, 256, 0, stream>>>(nms_s, nms_b, out_b, out_s, out_c, out_v);
}

// Round 20
// 104.668 us; speedup vs baseline: 1.2192x; 1.0001x over previous
//
#include <hip/hip_runtime.h>
#include <hip/hip_bf16.h>

typedef unsigned long long u64;
typedef unsigned int u32;

#define A_TOTAL 76725
#define NCLS 90
#define KTOP 5000u
#define MAXT 100
#define KTHR 0x3D4CCCCDu         /* bits of 0.05f */
#define TCAP 2048u               /* per-lane candidate capacity (total) */
#define SCAP 512u                /* per-slice capacity */
#define SELCAP 512u              /* fast-path >=T_b candidate cap */

__device__ __forceinline__ u64 pack_key(u32 k, u32 i) {
  return ((u64)k << 32) | (u64)(0xFFFFFFFFu - i);
}

// Full wave-0 cut with totals: B = smallest bucket with count(>=B) >= need.
__device__ __forceinline__ void cut4096w(const u32* hh, u32 need, int wl,
                                         u32& B, u32& incl, u32& above, u32& total) {
  int lo = wl << 6;
  u32 s = 0;
  #pragma unroll
  for (int j = 0; j < 64; ++j) s += hh[lo + j];
  u32 suf = s;
  #pragma unroll
  for (int off = 1; off < 64; off <<= 1) {
    u32 v = __shfl_down(suf, off, 64);
    if (wl < 64 - off) suf += v;
  }
  total = __shfl(suf, 0, 64);
  if (total < need) { B = 0; incl = total; above = 0; return; }
  u32 sufnext = suf - s;
  bool cross = (suf >= need) && (sufnext < need);
  u64 bal = __ballot(cross);
  int gl = (int)__ffsll((unsigned long long)bal) - 1;
  int glo = gl << 6;
  u32 aboveG = __shfl(sufnext, gl, 64);
  u32 hb = hh[glo + wl];
  u32 sufb = hb;
  #pragma unroll
  for (int off = 1; off < 64; off <<= 1) {
    u32 v = __shfl_down(sufb, off, 64);
    if (wl < 64 - off) sufb += v;
  }
  bool c2 = (aboveG + sufb >= need) && (aboveG + sufb - hb < need);
  u64 bal2 = __ballot(c2);
  int jB = (int)__ffsll((unsigned long long)bal2) - 1;
  B = (u32)(glo + jB);
  incl = aboveG + __shfl(sufb, jB, 64);
  above = incl - __shfl(hb, jB, 64);
}

// Block-cooperative descending bitonic sort of a[0..n) padded to pow2 with 0.
__device__ __forceinline__ void bitonic_desc(u64* a, u32 n, int tid, int nth) {
  u32 P = 2; while (P < n) P <<= 1;
  for (u32 i = tid; i < P; i += nth) if (i >= n) a[i] = 0ULL;
  __syncthreads();
  for (u32 kk = 2; kk <= P; kk <<= 1) {
    for (u32 jj = kk >> 1; jj; jj >>= 1) {
      for (u32 i = tid; i < P; i += nth) {
        u32 ixj = i ^ jj;
        if (ixj > i) {
          u64 x = a[i], y = a[ixj];
          bool up = ((i & kk) == 0);
          if (up ? (x < y) : (x > y)) { a[i] = y; a[ixj] = x; }
        }
      }
      __syncthreads();
    }
  }
}

// Wave-batch bitset greedy NMS over sorted candidates (single wave, no barriers).
__device__ __forceinline__ int bitset_scan(const u64* key_s, const float4* boxes4, size_t bbase,
                                           int C, float4* wbox, float4* bbox,
                                           float* outS, float* outB, int w, int wl) {
  int cur = 0;
  while (w < MAXT && cur < C) {
    int p = cur + wl;
    bool valid = (p < C);
    u64 kk = valid ? key_s[p] : 0ull;
    float4 mybox = make_float4(-3e30f, -3e30f, -3e30f, -3e30f);  // sentinel: zero overlap
    if (valid) {
      u32 idx = 0xFFFFFFFFu - (u32)(kk & 0xFFFFFFFFull);
      mybox = boxes4[bbase + idx];
    }
    bbox[wl] = mybox;
    float myarea = (mybox.z - mybox.x) * (mybox.w - mybox.y);
    bool alive = valid;
    for (int j = 0; j < w; ++j) {
      float4 pb = wbox[j];
      float yy1 = fmaxf(pb.x, mybox.x), xx1 = fmaxf(pb.y, mybox.y);
      float yy2 = fminf(pb.z, mybox.z), xx2 = fminf(pb.w, mybox.w);
      float inter = fmaxf(yy2 - yy1, 0.0f) * fmaxf(xx2 - xx1, 0.0f);
      bool bad = false;
      if (inter > 0.0f) {
        float pa = (pb.z - pb.x) * (pb.w - pb.y);
        bad = inter / (pa + myarea - inter + 1e-8f) > 0.3f;
      }
      alive = alive && !bad;
    }
    u64 krow = 0ull;
    int jmax = C - cur; if (jmax > 64) jmax = 64;
    for (int j = 0; j < jmax; ++j) {
      float4 pb = bbox[j];
      float yy1 = fmaxf(pb.x, mybox.x), xx1 = fmaxf(pb.y, mybox.y);
      float yy2 = fminf(pb.z, mybox.z), xx2 = fminf(pb.w, mybox.w);
      float inter = fmaxf(yy2 - yy1, 0.0f) * fmaxf(xx2 - xx1, 0.0f);
      bool kill = false;
      if (inter > 0.0f) {
        float pa = (pb.z - pb.x) * (pb.w - pb.y);
        kill = inter / (pa + myarea - inter + 1e-8f) > 0.3f;
      }
      if (kill) krow |= (1ull << j);
    }
    u32 krlo = (u32)krow, krhi = (u32)(krow >> 32);
    u64 amask = __ballot(alive);
    int myord = -1;
    while (amask != 0ull && w < MAXT) {
      int js = (int)__ffsll((unsigned long long)amask) - 1;
      u32 klo = __shfl(krlo, js, 64);
      u32 khi = __shfl(krhi, js, 64);
      u64 kr = ((u64)khi << 32) | (u64)klo;
      if (wl == js) myord = w;
      amask &= ~kr;
      amask &= ~(1ull << js);
      w++;
    }
    if (myord >= 0) {
      outS[myord] = __uint_as_float((u32)(kk >> 32));
      *(float4*)(outB + myord * 4) = mybox;
      wbox[myord] = mybox;
    }
    cur += 64;
  }
  return w;
}

// Wave-level lazy greedy NMS (fallback tier only; original semantics).
__device__ __forceinline__ int lazy_scan_g(const u64* key_s, const float4* boxes4, size_t bbase,
                                           int C, float4* wbox, float* outS, float* outB,
                                           int w, int wl) {
  int cur = 0;
  while (w < MAXT && cur < C) {
    int p = cur + wl;
    bool alive = (p < C);
    u64 kk = alive ? key_s[p] : 0ull;
    float4 mybox = make_float4(0.f, 0.f, 0.f, 0.f);
    if (alive) {
      u32 idx = 0xFFFFFFFFu - (u32)(kk & 0xFFFFFFFFull);
      mybox = boxes4[bbase + idx];
    }
    float myarea = (mybox.z - mybox.x) * (mybox.w - mybox.y);
    for (int j = 0; j < w; ++j) {
      float4 pb = wbox[j];
      float yy1 = fmaxf(pb.x, mybox.x), xx1 = fmaxf(pb.y, mybox.y);
      float yy2 = fminf(pb.z, mybox.z), xx2 = fminf(pb.w, mybox.w);
      float inter = fmaxf(yy2 - yy1, 0.0f) * fmaxf(xx2 - xx1, 0.0f);
      bool bad = false;
      if (inter > 0.0f) {
        float pa = (pb.z - pb.x) * (pb.w - pb.y);
        bad = inter / (pa + myarea - inter + 1e-8f) > 0.3f;
      }
      alive = alive && !bad;
    }
    for (;;) {
      u64 bal = __ballot(alive);
      if (bal == 0ull) break;
      int js = (int)__ffsll((unsigned long long)bal) - 1;
      float4 pb;
      pb.x = __shfl(mybox.x, js, 64);
      pb.y = __shfl(mybox.y, js, 64);
      pb.z = __shfl(mybox.z, js, 64);
      pb.w = __shfl(mybox.w, js, 64);
      u64 wk = __shfl(kk, js, 64);
      if (wl == 0) {
        outS[w] = __uint_as_float((u32)(wk >> 32));
        *(float4*)(outB + w * 4) = pb;
        wbox[w] = pb;
      }
      w++;
      if (w >= MAXT) break;
      if (wl <= js) alive = false;
      else if (alive) {
        float yy1 = fmaxf(pb.x, mybox.x), xx1 = fmaxf(pb.y, mybox.y);
        float yy2 = fminf(pb.z, mybox.z), xx2 = fminf(pb.w, mybox.w);
        float inter = fmaxf(yy2 - yy1, 0.0f) * fmaxf(xx2 - xx1, 0.0f);
        if (inter > 0.0f) {
          float pa = (pb.z - pb.x) * (pb.w - pb.y);
          if (inter / (pa + myarea - inter + 1e-8f) > 0.3f) alive = false;
        }
      }
    }
    cur += 64;
  }
  return w;
}

// ---------------- workspace zeroing ----------------
__global__ __launch_bounds__(256) void zero_kernel(u32* __restrict__ p, int n) {
  int i = blockIdx.x * 256 + threadIdx.x;
  if (i < n) p[i] = 0;
}

// ---------------- fused decode+clip (blocks 0..599) and streaming collect (600..7439) ----------------
__device__ __forceinline__ void coll_elem(int i, float x, int b, int base, int slice,
                                          u64* __restrict__ listT_g, u32* __restrict__ cnt_pad) {
  if (x >= 0.0f) {                  // s >= 0.5
    u32 a = (u32)i / 91u;           // compile-time magic-mul
    u32 c = (u32)i - a * 91u;
    if (c != 0u) {
      float s = 1.0f / (1.0f + expf(-x));
      int lane = b * NCLS + (int)c - 1;
      u32 idx = (u32)base + a;
      u32 p = atomicAdd(&cnt_pad[lane * 128 + slice * 16], 1u);
      if (p < SCAP) listT_g[(((size_t)lane * 8 + slice) << 9) + p] = pack_key(__float_as_uint(s), idx);
    }
  }
}

__global__ __launch_bounds__(256) void front_kernel(
    const float* __restrict__ bx0, const float* __restrict__ bx1, const float* __restrict__ bx2,
    const float* __restrict__ bx3, const float* __restrict__ bx4,
    const float* __restrict__ an0, const float* __restrict__ an1, const float* __restrict__ an2,
    const float* __restrict__ an3, const float* __restrict__ an4,
    const float* __restrict__ c3, const float* __restrict__ c4, const float* __restrict__ c5,
    const float* __restrict__ c6, const float* __restrict__ c7,
    const float* __restrict__ img, float* __restrict__ boxes,
    u64* __restrict__ listT_g, u32* __restrict__ cnt_pad)
{
  int blk = blockIdx.x, tid = threadIdx.x;
  if (blk < 600) {
    int t = blk * 256 + tid;
    if (t >= 2 * A_TOTAL) return;
    int b = t / A_TOTAL, a = t % A_TOTAL;
    const float* bp; const float* ap; int al; int nl;
    if (a < 57600)      { bp = bx0; ap = an0; al = a;          nl = 57600; }
    else if (a < 72000) { bp = bx1; ap = an1; al = a - 57600;  nl = 14400; }
    else if (a < 75600) { bp = bx2; ap = an2; al = a - 72000;  nl = 3600;  }
    else if (a < 76500) { bp = bx3; ap = an3; al = a - 75600;  nl = 900;   }
    else                { bp = bx4; ap = an4; al = a - 76500;  nl = 225;   }
    float4 e  = *(const float4*)(bp + ((size_t)b * nl + al) * 4);
    float4 an = *(const float4*)(ap + ((size_t)b * nl + al) * 4);
    const float CLIP = 4.135166556742356f; // log(1000/16)
    float ah  = an.z - an.x + 1.0f;
    float aw  = an.w - an.y + 1.0f;
    float ayc = an.x + 0.5f * ah;
    float axc = an.y + 0.5f * aw;
    float dh = fminf(e.z, CLIP), dw = fminf(e.w, CLIP);
    float yc = e.x * ah + ayc;
    float xc = e.y * aw + axc;
    float h  = expf(dh) * ah;
    float w  = expf(dw) * aw;
    float ymin = yc - 0.5f * h;
    float xmin = xc - 0.5f * w;
    float ymax = ymin + h - 1.0f;
    float xmax = xmin + w - 1.0f;
    float H = img[b * 2 + 0], W = img[b * 2 + 1];
    float4 o;
    o.x = fminf(fmaxf(ymin, 0.0f), H);
    o.y = fminf(fmaxf(xmin, 0.0f), W);
    o.z = fminf(fmaxf(ymax, 0.0f), H);
    o.w = fminf(fmaxf(xmax, 0.0f), W);
    *(float4*)(boxes + (size_t)t * 4) = o;
    return;
  }
  // ---- streaming collect, doubled parallelism (2 float4 iters/thread at L0-L3) ----
  int blk2 = blk - 600;
  int slice = blk2 & 7;
  const float* cls; int n, base, b, loc, J, lvl;
  if (blk2 < 5120)      { lvl = 0; cls = c3; n = 57600; base = 0;     J = 2560; int r = blk2;        b = r >= J; loc = b ? r - J : r; }
  else if (blk2 < 6400) { lvl = 1; cls = c4; n = 14400; base = 57600; J = 640;  int r = blk2 - 5120; b = r >= J; loc = b ? r - J : r; }
  else if (blk2 < 6720) { lvl = 2; cls = c5; n = 3600;  base = 72000; J = 160;  int r = blk2 - 6400; b = r >= J; loc = b ? r - J : r; }
  else if (blk2 < 6800) { lvl = 3; cls = c6; n = 900;   base = 75600; J = 40;   int r = blk2 - 6720; b = r >= J; loc = b ? r - J : r; }
  else                  { lvl = 4; cls = c7; n = 225;   base = 76500; J = 20;   int r = blk2 - 6800; b = r >= J; loc = b ? r - J : r; }

  if (lvl <= 3) {
    int F4 = n * 91 / 4;
    int chunk = (F4 + J - 1) / J;
    int q0 = loc * chunk;
    int q1 = q0 + chunk; if (q1 > F4) q1 = F4;
    const float4* src4 = (const float4*)(cls + (size_t)b * n * 91);
    for (int q = q0 + tid; q < q1; q += 256) {
      float4 v = src4[q];
      int i0 = q << 2;
      coll_elem(i0,     v.x, b, base, slice, listT_g, cnt_pad);
      coll_elem(i0 + 1, v.y, b, base, slice, listT_g, cnt_pad);
      coll_elem(i0 + 2, v.z, b, base, slice, listT_g, cnt_pad);
      coll_elem(i0 + 3, v.w, b, base, slice, listT_g, cnt_pad);
    }
  } else {
    int F = n * 91;                 // 20475 (not /4-divisible) -> scalar
    int chunk = (F + J - 1) / J;
    int s0 = loc * chunk;
    int s1 = s0 + chunk; if (s1 > F) s1 = F;
    const float* src = cls + (size_t)b * F;
    for (int i = s0 + tid; i < s1; i += 256) coll_elem(i, src[i], b, base, slice, listT_g, cnt_pad);
  }
}

// ---------------- phase 1: per-lane top-8 prefix greedy -> true winner subset ----------------
__global__ __launch_bounds__(256) void top8_kernel(
    const u64* __restrict__ listT_g, const u32* __restrict__ cnt_pad,
    const float* __restrict__ boxes, u32* __restrict__ win8, u32* __restrict__ w8cnt)
{
  __shared__ u64 wred[4];
  __shared__ u64 sh_top;
  __shared__ u64 topk[8];
  __shared__ float4 tb[8];
  int tid = threadIdx.x;
  int lane = blockIdx.x;

  u32 pre[9]; pre[0] = 0;
  bool of = false;
  #pragma unroll
  for (int j = 0; j < 8; ++j) {
    u32 cj = cnt_pad[lane * 128 + j * 16];
    of |= (cj > SCAP);
    pre[j + 1] = pre[j] + cj;
  }
  u32 cnt = pre[8];
  if (of || cnt > TCAP) { if (tid == 0) w8cnt[lane] = 0xFFFFu; return; }

  u64 kr[8];
  #pragma unroll
  for (int r = 0; r < 8; ++r) {
    u32 s = (u32)tid + (u32)r * 256u;
    u64 k = 0ull;
    if (s < cnt) {
      u32 j = 0;
      #pragma unroll
      for (int t = 1; t < 8; ++t) if (s >= pre[t]) j = (u32)t;
      k = listT_g[(((size_t)lane * 8 + j) << 9) + (s - pre[j])];
    }
    kr[r] = k;
  }

  int nt = 0;
  for (int it = 0; it < 8; ++it) {
    u64 m = kr[0];
    #pragma unroll
    for (int r = 1; r < 8; ++r) if (kr[r] > m) m = kr[r];
    #pragma unroll
    for (int off = 1; off < 64; off <<= 1) {
      u64 o = __shfl_xor(m, off);
      if (o > m) m = o;
    }
    if ((tid & 63) == 0) wred[tid >> 6] = m;
    __syncthreads();
    if (tid == 0) {
      u64 w = wred[0];
      if (wred[1] > w) w = wred[1];
      if (wred[2] > w) w = wred[2];
      if (wred[3] > w) w = wred[3];
      sh_top = w;
      topk[it] = w;
    }
    __syncthreads();
    u64 ch = sh_top;
    if (ch == 0ull) break;
    #pragma unroll
    for (int r = 0; r < 8; ++r) if (kr[r] == ch) kr[r] = 0ull;   // keys unique
    nt = it + 1;
  }
  __syncthreads();
  const float4* boxes4 = (const float4*)boxes;
  size_t bbase = (size_t)(lane / NCLS) * A_TOTAL;
  if (tid < nt) {
    u32 idx = 0xFFFFFFFFu - (u32)(topk[tid] & 0xFFFFFFFFull);
    tb[tid] = boxes4[bbase + idx];
  }
  __syncthreads();
  if (tid == 0) {
    float4 abox[8];
    int w8 = 0;
    for (int i = 0; i < nt; ++i) {
      float4 mb = tb[i];
      float ma = (mb.z - mb.x) * (mb.w - mb.y);
      bool alive = true;
      for (int j = 0; j < w8; ++j) {
        float4 pb = abox[j];
        float yy1 = fmaxf(pb.x, mb.x), xx1 = fmaxf(pb.y, mb.y);
        float yy2 = fminf(pb.z, mb.z), xx2 = fminf(pb.w, mb.w);
        float inter = fmaxf(yy2 - yy1, 0.0f) * fmaxf(xx2 - xx1, 0.0f);
        if (inter > 0.0f) {
          float pa = (pb.z - pb.x) * (pb.w - pb.y);
          if (inter / (pa + ma - inter + 1e-8f) > 0.3f) alive = false;
        }
      }
      if (alive) {
        win8[lane * 8 + w8] = (u32)(topk[i] >> 32);
        abox[w8] = mb;
        w8++;
      }
    }
    w8cnt[lane] = (u32)w8;
  }
}

// ---------------- phase 2: per-batch T_b lower bound via 4096-bucket histogram ----------------
__global__ __launch_bounds__(256) void tlb2_kernel(const u32* __restrict__ win8,
                                                   const u32* __restrict__ w8cnt,
                                                   u32* __restrict__ tparams)
{
  __shared__ u32 hist[4096];
  __shared__ u32 sh_tot, sh_panic;
  __shared__ u32 sh_B, sh_total;
  int t = threadIdx.x;
  if (t == 0) sh_panic = 0;
  __syncthreads();
  for (int b = 0; b < 2; ++b) {
    for (int i = t; i < 4096; i += 256) hist[i] = 0;
    if (t == 0) sh_tot = 0;
    __syncthreads();
    u32 mycnt = 0;
    for (int i = t; i < 720; i += 256) {
      int ln = b * NCLS + i / 8;
      u32 cc = w8cnt[ln];
      if (cc == 0xFFFFu) { sh_panic = 1; }
      else if ((u32)(i & 7) < cc) {
        u32 v = win8[ln * 8 + (i & 7)];
        atomicAdd(&hist[v >> 19], 1u);
        mycnt++;
      }
    }
    atomicAdd(&sh_tot, mycnt);
    __syncthreads();
    if (t < 64) {
      u32 Bx, ix, ax, tx;
      cut4096w(hist, 100u, t, Bx, ix, ax, tx);
      if (t == 0) { sh_B = Bx; sh_total = tx; }
    }
    __syncthreads();
    if (t == 0) {
      tparams[b] = sh_B << 19;               // lower bound on 100th-largest winner score bits
      if (sh_tot < 100u || sh_total < 100u) sh_panic = 1;
    }
    __syncthreads();
  }
  if (t == 0) tparams[2] = sh_panic;
}

// ---------------- per-lane NMS: T_b fast path + exact in-kernel fallback ----------------
__global__ __launch_bounds__(256) void nms_kernel(
    const float* __restrict__ c3, const float* __restrict__ c4, const float* __restrict__ c5,
    const float* __restrict__ c6, const float* __restrict__ c7,
    const float* __restrict__ boxes, const u64* __restrict__ listT_g,
    const u32* __restrict__ cnt_pad, const u32* __restrict__ tparams,
    float* __restrict__ nms_s, float* __restrict__ nms_b)
{
  __shared__ __align__(16) char big[40960];     // fallback: listA u64[5120] -> cntArr u32[4096]
  __shared__ __align__(16) u64 listE[2048];     // fallback only
  __shared__ u64 key_s[2048];
  __shared__ __align__(16) u32 histL[4096];     // fallback hist; fast path: sel u64[SELCAP]
  __shared__ float4 wbox[MAXT];
  __shared__ float4 bbox[64];
  __shared__ u32 wtot[4];
  __shared__ u32 sh_flag, sh_cS;
  __shared__ u64 sh_minPrev;
  __shared__ u32 sh_w, sh_done, sh_eidx, sh_Rthr, sh_eSorted, sh_bigF;
  __shared__ u32 sh_B, sh_incl, sh_above, sh_total, sh_cA, sh_cE, sh_B2;

  int tid = threadIdx.x;
  int lane = blockIdx.x;
  int b = lane / NCLS, c = lane % NCLS;
  const float4* boxes4 = (const float4*)boxes;
  size_t bbase = (size_t)b * A_TOTAL;
  const u64 thrpack = ((u64)KTHR) << 32;

  float* outS = nms_s + (size_t)lane * MAXT;
  float* outB = nms_b + (size_t)lane * MAXT * 4;

  u32 pre[9]; pre[0] = 0;
  bool of = false;
  #pragma unroll
  for (int j = 0; j < 8; ++j) {
    u32 cj = cnt_pad[lane * 128 + j * 16];
    of |= (cj > SCAP);
    pre[j + 1] = pre[j] + cj;
  }
  u32 cnt = pre[8];
  u32 Tlb = tparams[b], panic = tparams[2];
  if (tid == 0) { sh_flag = (of || cnt > TCAP || panic) ? 1u : 0u; sh_cS = 0; }
  __syncthreads();

  if (!sh_flag) {
    // fast path: only candidates >= T_b can reach the final per-batch top-100
    const u64 Tpack = ((u64)Tlb) << 32;
    u64* sel = (u64*)histL;
    #pragma unroll
    for (int r = 0; r < 8; ++r) {
      u32 s = (u32)tid + (u32)r * 256u;
      if (s < cnt) {
        u32 j = 0;
        #pragma unroll
        for (int t = 1; t < 8; ++t) if (s >= pre[t]) j = (u32)t;
        u64 k = listT_g[(((size_t)lane * 8 + j) << 9) + (s - pre[j])];
        if (k >= Tpack) {
          u32 p = atomicAdd(&sh_cS, 1u);
          if (p < SELCAP) sel[p] = k;
        }
      }
    }
    __syncthreads();
    u32 Cs = sh_cS;
    if (Cs > SELCAP) {
      if (tid == 0) sh_flag = 1;
    } else {
      for (u32 j = tid; j < Cs; j += 256) {
        u64 kj = sel[j];
        u32 rk = 0;
        for (u32 i2 = 0; i2 < Cs; ++i2) rk += (sel[i2] > kj) ? 1u : 0u;
        key_s[rk] = kj;
      }
      __syncthreads();
      if (tid < 64) {
        int w = bitset_scan(key_s, boxes4, bbase, (int)Cs, wbox, bbox, outS, outB, 0, tid);
        if (tid == 0) sh_w = (u32)w;     // w < MAXT expected: rest provably below final top-100
      }
    }
  }
  __syncthreads();
  if (!sh_flag) {
    u32 w = sh_w;
    for (u32 p = w + (u32)tid; p < MAXT; p += 256) {
      outS[p] = -1.0f;
      *(float4*)(outB + p * 4) = make_float4(0.f, 0.f, 0.f, 0.f);
    }
    return;
  }

  // ================= EXACT FALLBACK (rare): rebuild from raw column =================
  auto sb_of = [&](int i) -> u32 {
    const float* p; int al, nl;
    if (i < 57600)      { p = c3; al = i;          nl = 57600; }
    else if (i < 72000) { p = c4; al = i - 57600;  nl = 14400; }
    else if (i < 75600) { p = c5; al = i - 72000;  nl = 3600;  }
    else if (i < 76500) { p = c6; al = i - 75600;  nl = 900;   }
    else                { p = c7; al = i - 76500;  nl = 225;   }
    float x = p[((size_t)b * nl + al) * 91 + (c + 1)];
    float s = 1.0f / (1.0f + expf(-x));
    return __float_as_uint(s);
  };

  u64* listA = (u64*)big;
  for (int i = tid; i < 4096; i += 256) histL[i] = 0;
  if (tid == 0) {
    sh_cA = 0; sh_cE = 0; sh_w = 0; sh_done = 0; sh_eidx = 0; sh_eSorted = 0; sh_minPrev = ~0ull;
  }
  __syncthreads();
  for (int i = tid; i < A_TOTAL; i += 256) atomicAdd(&histL[sb_of(i) >> 19], 1u);
  __syncthreads();
  if (tid < 64) {
    u32 Bx, ix, ax, tx;
    cut4096w(histL, KTOP, tid, Bx, ix, ax, tx);
    if (tid == 0) sh_B = Bx;
  }
  __syncthreads();
  u32 B = sh_B;
  for (int i = tid; i < A_TOTAL; i += 256) {
    u32 u = sb_of(i);
    u32 bkt = u >> 19;
    if (bkt > B) {
      u32 p = atomicAdd(&sh_cA, 1u);
      if (p < 5120u) listA[p] = pack_key(u, (u32)i);
    } else if (bkt == B) {
      u32 p = atomicAdd(&sh_cE, 1u);
      if (p < 2048u) listE[p] = pack_key(u, (u32)i);
    }
  }
  __syncthreads();
  u32 g = sh_cA, h = sh_cE;
  if (h > 2048u) {
    for (int i = tid; i < 4096; i += 256) histL[i] = 0;
    if (tid == 0) sh_cE = 0;
    __syncthreads();
    for (int i = tid; i < A_TOTAL; i += 256) {
      u32 u = sb_of(i);
      if ((u >> 19) == B) atomicAdd(&histL[(u >> 7) & 0xFFFu], 1u);
    }
    __syncthreads();
    u32 R1 = KTOP - g;
    if (tid < 64) {
      u32 Bx, ix, ax, tx;
      cut4096w(histL, R1, tid, Bx, ix, ax, tx);
      if (tid == 0) sh_B2 = Bx;
    }
    __syncthreads();
    u32 B2 = sh_B2;
    for (int i = tid; i < A_TOTAL; i += 256) {
      u32 u = sb_of(i);
      if ((u >> 19) == B) {
        u32 sb2 = (u >> 7) & 0xFFFu;
        if (sb2 > B2) {
          u32 p = atomicAdd(&sh_cA, 1u);
          if (p < 5120u) listA[p] = pack_key(u, (u32)i);
        } else if (sb2 == B2) {
          u32 p = atomicAdd(&sh_cE, 1u);
          if (p < 2048u) listE[p] = pack_key(u, (u32)i);
        }
      }
    }
    __syncthreads();
    g = sh_cA; h = sh_cE; if (h > 2048u) h = 2048u;
  }
  if (g > 5120u) g = 5120u;
  u32 R = (g < KTOP) ? (KTOP - g) : 0u; if (R > h) R = h;

  u64 ak[20];
  #pragma unroll
  for (int r = 0; r < 20; ++r) {
    u32 s2 = (u32)tid + (u32)r * 256u;
    u64 kp = (s2 < g) ? listA[s2] : 0ull;
    if (kp < thrpack) kp = 0ull;
    ak[r] = kp;
  }
  __syncthreads();
  u32* cntArr = (u32*)big;

  const float LO0  = 0.04f;
  const float INV0 = 4096.0f / (1.001f - 0.04f);

  for (int seg = 0; seg < 7200; ++seg) {
    __syncthreads();
    if (sh_w >= MAXT || sh_done) break;
    u64 minPrev = sh_minPrev;

    int digLvl = 0;
    u32 A_B0 = 0, A_B1 = 0;
    float lo1 = 0.f, inv1 = 0.f;
    u64 kMask = 0, kPref = 0;
    int m1shift = 32;
    int selMode = -1;
    u32 selB = 0;
    u32 C = 0;
    bool fromE = false;

    for (int lvl = 0; lvl < 8; ++lvl) {
      for (int i = tid; i < 4096; i += 256) histL[i] = 0;
      __syncthreads();
      #pragma unroll
      for (int r = 0; r < 20; ++r) {
        u64 k = ak[r];
        if (!k || k >= minPrev) continue;
        float s = __uint_as_float((u32)(k >> 32));
        if (digLvl >= 1) { int d0 = (int)((s - LO0) * INV0); d0 = min(max(d0, 0), 4095); if ((u32)d0 != A_B0) continue; }
        if (digLvl >= 2) { int d1 = (int)((s - lo1) * inv1); d1 = min(max(d1, 0), 4095); if ((u32)d1 != A_B1) continue; }
        if (digLvl >= 3 && ((k & kMask) != kPref)) continue;
        u32 d;
        if (digLvl == 0)      { int t0 = (int)((s - LO0) * INV0); d = (u32)min(max(t0, 0), 4095); }
        else if (digLvl == 1) { int t1 = (int)((s - lo1) * inv1); d = (u32)min(max(t1, 0), 4095); }
        else                  d = (u32)((k >> m1shift) & 0xFFFull);
        atomicAdd(&histL[d], 1u);
      }
      __syncthreads();
      if (tid < 64) {
        u32 Bx, ix, ax, tx;
        cut4096w(histL, 1024u, tid, Bx, ix, ax, tx);
        if (tid == 0) { sh_B = Bx; sh_incl = ix; sh_above = ax; sh_total = tx; }
      }
      __syncthreads();
      u32 total = sh_total, incl = sh_incl, above = sh_above, Bx = sh_B;
      if (total == 0u)   { fromE = true; break; }
      if (total < 1024u) { selMode = 0; C = total; break; }
      if (incl <= 2048u) { selMode = 1; selB = Bx; C = incl; break; }
      if (above > 0u)    { selMode = 2; selB = Bx; C = above; break; }
      if (digLvl == 0) {
        A_B0 = Bx;
        lo1 = LO0 + (float)Bx / INV0;
        inv1 = INV0 * 4096.0f;
        digLvl = 1;
      } else if (digLvl == 1) {
        A_B1 = Bx;
        digLvl = 2; m1shift = 32;
      } else {
        kPref |= ((u64)Bx << m1shift);
        kMask |= (0xFFFull << m1shift);
        m1shift -= 12;
        digLvl++;
      }
      __syncthreads();
    }

    if (fromE) {
      if (!sh_eSorted) {
        bitonic_desc(listE, h, tid, 256);
        if (tid == 0) {
          u32 lo = 0, hi2 = h;
          while (lo < hi2) { u32 mid = (lo + hi2) >> 1; if (listE[mid] >= thrpack) lo = mid + 1; else hi2 = mid; }
          sh_Rthr = (R < lo) ? R : lo;
          sh_eSorted = 1;
        }
        __syncthreads();
      }
      u32 eidx = sh_eidx;
      u32 take = (sh_Rthr > eidx) ? (sh_Rthr - eidx) : 0u;
      if (take > 2048u) take = 2048u;
      if (take == 0u) { if (tid == 0) sh_done = 1; continue; }
      for (u32 i = tid; i < take; i += 256) key_s[i] = listE[eidx + i];
      C = take;
      if (tid == 0) sh_eidx = eidx + take;
    } else {
      u32 hloc[16];
      {
        int t0 = tid << 4;
        u32 ssum = 0;
        #pragma unroll
        for (int j = 0; j < 16; ++j) { hloc[j] = histL[t0 + j]; ssum += hloc[j]; }
        int wl = tid & 63, wid = tid >> 6;
        u32 suf = ssum;
        #pragma unroll
        for (int off = 1; off < 64; off <<= 1) {
          u32 v = __shfl_down(suf, off, 64);
          if (wl < 64 - off) suf += v;
        }
        if (wl == 0) wtot[wid] = suf;
        __syncthreads();
        u32 cross = 0;
        for (int w2 = wid + 1; w2 < 4; ++w2) cross += wtot[w2];
        u32 run = (suf - ssum) + cross;
        #pragma unroll
        for (int j = 15; j >= 0; --j) { u32 base2 = run; run += hloc[j]; histL[t0 + j] = base2; }
      }
      for (int i = tid; i < 4096; i += 256) cntArr[i] = 0;
      if (tid == 0) sh_bigF = 0;
      __syncthreads();
      #pragma unroll
      for (int r = 0; r < 20; ++r) {
        u64 k = ak[r];
        if (!k || k >= minPrev) continue;
        float s = __uint_as_float((u32)(k >> 32));
        if (digLvl >= 1) { int d0 = (int)((s - LO0) * INV0); d0 = min(max(d0, 0), 4095); if ((u32)d0 != A_B0) continue; }
        if (digLvl >= 2) { int d1 = (int)((s - lo1) * inv1); d1 = min(max(d1, 0), 4095); if ((u32)d1 != A_B1) continue; }
        if (digLvl >= 3 && ((k & kMask) != kPref)) continue;
        u32 d;
        if (digLvl == 0)      { int t0x = (int)((s - LO0) * INV0); d = (u32)min(max(t0x, 0), 4095); }
        else if (digLvl == 1) { int t1x = (int)((s - lo1) * inv1); d = (u32)min(max(t1x, 0), 4095); }
        else                  d = (u32)((k >> m1shift) & 0xFFFull);
        if (selMode == 1)      { if (d < selB) continue; }
        else if (selMode == 2) { if (d <= selB) continue; }
        u32 pos = histL[d] + atomicAdd(&cntArr[d], 1u);
        if (pos < 2048u) key_s[pos] = k;
      }
      __syncthreads();
      {
        int t0 = tid << 4;
        for (int j = 0; j < 16; ++j) {
          u32 bkt = (u32)(t0 + j);
          u32 cc = cntArr[bkt];
          if (cc >= 2u) {
            if (cc <= 48u) {
              u32 basep = histL[bkt];
              for (u32 a2 = 1; a2 < cc; ++a2) {
                u64 kv = key_s[basep + a2];
                int bi = (int)a2 - 1;
                while (bi >= 0 && key_s[basep + bi] < kv) { key_s[basep + bi + 1] = key_s[basep + bi]; --bi; }
                key_s[basep + bi + 1] = kv;
              }
            } else sh_bigF = 1;
          }
        }
      }
      __syncthreads();
      if (sh_bigF) bitonic_desc(key_s, C, tid, 256);
      if (tid == 0) sh_minPrev = key_s[C - 1];
    }
    __syncthreads();

    if (tid < 64) {
      int w = lazy_scan_g(key_s, boxes4, bbase, (int)C, wbox, outS, outB, (int)sh_w, tid);
      if (tid == 0) sh_w = (u32)w;
    }
  }

  __syncthreads();
  u32 w = sh_w;
  for (u32 p = w + (u32)tid; p < MAXT; p += 256) {
    outS[p] = -1.0f;
    *(float4*)(outB + p * 4) = make_float4(0.f, 0.f, 0.f, 0.f);
  }
}

// ---------------- final per-batch top-100: radix rank-select ----------------
__global__ __launch_bounds__(256) void merge_kernel(
    const float* __restrict__ nms_s, const float* __restrict__ nms_b,
    float* __restrict__ out_b, float* __restrict__ out_s,
    float* __restrict__ out_c, float* __restrict__ out_v)
{
  __shared__ u64 keys[NCLS * MAXT];   // 72 KB
  __shared__ u32 hist[4096];          // 16 KB
  __shared__ u64 sel[640];
  __shared__ u32 sh_cnt, sh_valid;
  __shared__ u32 sh_B, sh_incl, sh_above, sh_total;

  int b = blockIdx.x, tid = threadIdx.x;
  const int NTOT = NCLS * MAXT;

  for (int i = tid; i < NTOT; i += 256) {
    float s = nms_s[(size_t)b * NTOT + i];
    u32 u = __float_as_uint(s);
    u = (u & 0x80000000u) ? ~u : (u | 0x80000000u);
    keys[i] = ((u64)u << 32) | (u64)(0xFFFFFFFFu - (u32)i);
  }
  if (tid == 0) { sh_cnt = 0; sh_valid = 0; }

  u64 prefVal = 0;
  u64 T = 0;
  u32 need = MAXT;
  const int shifts[6] = {52, 40, 28, 16, 4, 0};
  const int widths[6] = {12, 12, 12, 12, 12, 4};
  for (int lvl = 0; lvl < 6; ++lvl) {
    int s = shifts[lvl], w = widths[lvl];
    for (int i = tid; i < 4096; i += 256) hist[i] = 0;
    __syncthreads();
    u32 dmask = (1u << w) - 1u;
    for (int i = tid; i < NTOT; i += 256) {
      u64 k = keys[i];
      if (lvl > 0 && (k >> (s + w)) != (prefVal >> (s + w))) continue;
      atomicAdd(&hist[(u32)((k >> s) & dmask)], 1u);
    }
    __syncthreads();
    if (tid < 64) {
      u32 Bx, ix, ax, tx;
      cut4096w(hist, need, tid, Bx, ix, ax, tx);
      if (tid == 0) { sh_B = Bx; sh_incl = ix; sh_above = ax; sh_total = tx; }
    }
    __syncthreads();
    u32 B = sh_B, incl = sh_incl, above = sh_above;
    if (incl <= 512u || lvl == 5) {
      T = prefVal | ((u64)B << s);
      break;
    }
    prefVal |= ((u64)B << s);
    need -= above;
  }
  __syncthreads();

  for (int i = tid; i < NTOT; i += 256) {
    u64 k = keys[i];
    if (k >= T) {
      u32 p = atomicAdd(&sh_cnt, 1u);
      if (p < 640u) sel[p] = k;
    }
  }
  __syncthreads();
  u32 cnt = sh_cnt; if (cnt > 640u) cnt = 640u;

  for (u32 j = tid; j < cnt; j += 256) {
    u64 kj = sel[j];
    u32 r = 0;
    for (u32 i = 0; i < cnt; ++i) r += (sel[i] > kj) ? 1u : 0u;
    if (r < (u32)MAXT) {
      u32 u = (u32)(kj >> 32);
      u32 bits = (u & 0x80000000u) ? (u ^ 0x80000000u) : ~u;
      float sc = __uint_as_float(bits);
      u32 flat = 0xFFFFFFFFu - (u32)(kj & 0xFFFFFFFFull);
      int cls = (int)(flat / MAXT), pos = (int)(flat % MAXT);
      out_s[b * MAXT + r] = sc;
      out_c[b * MAXT + r] = (float)(cls + 1);
      *(float4*)(out_b + ((size_t)b * MAXT + r) * 4) =
          *(const float4*)(nms_b + (((size_t)b * NCLS + cls) * MAXT + pos) * 4);
      if (sc > -1.0f) atomicAdd(&sh_valid, 1u);
    }
  }
  __syncthreads();
  if (tid == 0) out_v[b] = (float)sh_valid;
}

extern "C" void kernel_launch(void* const* d_in, const int* in_sizes, int n_in,
                              void* d_out, int out_size, void* d_ws, size_t ws_size,
                              hipStream_t stream)
{
  const float* box[5]; const float* cls[5]; const float* anc[5];
  bool interleaved = (in_sizes[1] == 2 * 57600 * 91);   // setup_inputs dict order
  if (interleaved) {
    for (int l = 0; l < 5; ++l) {
      box[l] = (const float*)d_in[3 * l + 0];
      cls[l] = (const float*)d_in[3 * l + 1];
      anc[l] = (const float*)d_in[3 * l + 2];
    }
  } else {
    for (int l = 0; l < 5; ++l) {
      box[l] = (const float*)d_in[l];
      cls[l] = (const float*)d_in[5 + l];
      anc[l] = (const float*)d_in[10 + l];
    }
  }
  const float* img = (const float*)d_in[15];

  float* ws = (float*)d_ws;
  float* boxes_ws = ws;                              // 613800 f
  u32*   cnt_pad  = (u32*)(boxes_ws + 613800);       // 180*128 u32 (8 slices x 64B stride)
  u32*   win8     = cnt_pad + 180 * 128;             // 180*8 u32
  u32*   w8cnt    = win8 + 180 * 8;                  // 180 u32
  u32*   tparams  = w8cnt + 180;                     // 4 u32 (T0, T1, panic, pad)
  u64*   listT_g  = (u64*)(tparams + 4);             // 180*8*512 u64
  float* nms_s    = (float*)(listT_g + 180 * 8 * 512); // 18000 f
  float* nms_b    = nms_s + 18000;                   // 72000 f

  const int NZ = 180 * 128;
  zero_kernel<<<(NZ + 255) / 256, 256, 0, stream>>>(cnt_pad, NZ);

  front_kernel<<<7440, 256, 0, stream>>>(
      box[0], box[1], box[2], box[3], box[4],
      anc[0], anc[1], anc[2], anc[3], anc[4],
      cls[0], cls[1], cls[2], cls[3], cls[4],
      img, boxes_ws, listT_g, cnt_pad);

  top8_kernel<<<180, 256, 0, stream>>>(listT_g, cnt_pad, boxes_ws, win8, w8cnt);

  tlb2_kernel<<<1, 256, 0, stream>>>(win8, w8cnt, tparams);

  nms_kernel<<<180, 256, 0, stream>>>(cls[0], cls[1], cls[2], cls[3], cls[4],
                                      boxes_ws, listT_g, cnt_pad, tparams, nms_s, nms_b);

  float* out_b = (float*)d_out;  // [2][100][4]
  float* out_s = out_b + 800;    // [2][100]
  float* out_c = out_s + 200;    // [2][100]
  float* out_v = out_c + 200;    // [2]
  merge_kernel<<<2, 256, 0, stream>>>(nms_s, nms_b, out_b, out_s, out_c, out_v);
}

// Round 22
// 104.361 us; speedup vs baseline: 1.2228x; 1.0029x over previous
//
#include <hip/hip_runtime.h>
#include <hip/hip_bf16.h>

typedef unsigned long long u64;
typedef unsigned int u32;

#define A_TOTAL 76725
#define NCLS 90
#define KTOP 5000u
#define MAXT 100
#define KTHR 0x3D4CCCCDu         /* bits of 0.05f */
#define TCAP 2048u               /* per-lane candidate capacity (total) */
#define SCAP 512u                /* per-slice capacity */
#define SELCAP 512u              /* fast-path >=T_b candidate cap */

__device__ __forceinline__ u64 pack_key(u32 k, u32 i) {
  return ((u64)k << 32) | (u64)(0xFFFFFFFFu - i);
}

// Full wave-0 cut with totals: B = smallest bucket with count(>=B) >= need.
__device__ __forceinline__ void cut4096w(const u32* hh, u32 need, int wl,
                                         u32& B, u32& incl, u32& above, u32& total) {
  int lo = wl << 6;
  u32 s = 0;
  #pragma unroll
  for (int j = 0; j < 64; ++j) s += hh[lo + j];
  u32 suf = s;
  #pragma unroll
  for (int off = 1; off < 64; off <<= 1) {
    u32 v = __shfl_down(suf, off, 64);
    if (wl < 64 - off) suf += v;
  }
  total = __shfl(suf, 0, 64);
  if (total < need) { B = 0; incl = total; above = 0; return; }
  u32 sufnext = suf - s;
  bool cross = (suf >= need) && (sufnext < need);
  u64 bal = __ballot(cross);
  int gl = (int)__ffsll((unsigned long long)bal) - 1;
  int glo = gl << 6;
  u32 aboveG = __shfl(sufnext, gl, 64);
  u32 hb = hh[glo + wl];
  u32 sufb = hb;
  #pragma unroll
  for (int off = 1; off < 64; off <<= 1) {
    u32 v = __shfl_down(sufb, off, 64);
    if (wl < 64 - off) sufb += v;
  }
  bool c2 = (aboveG + sufb >= need) && (aboveG + sufb - hb < need);
  u64 bal2 = __ballot(c2);
  int jB = (int)__ffsll((unsigned long long)bal2) - 1;
  B = (u32)(glo + jB);
  incl = aboveG + __shfl(sufb, jB, 64);
  above = incl - __shfl(hb, jB, 64);
}

// Block-cooperative descending bitonic sort of a[0..n) padded to pow2 with 0.
__device__ __forceinline__ void bitonic_desc(u64* a, u32 n, int tid, int nth) {
  u32 P = 2; while (P < n) P <<= 1;
  for (u32 i = tid; i < P; i += nth) if (i >= n) a[i] = 0ULL;
  __syncthreads();
  for (u32 kk = 2; kk <= P; kk <<= 1) {
    for (u32 jj = kk >> 1; jj; jj >>= 1) {
      for (u32 i = tid; i < P; i += nth) {
        u32 ixj = i ^ jj;
        if (ixj > i) {
          u64 x = a[i], y = a[ixj];
          bool up = ((i & kk) == 0);
          if (up ? (x < y) : (x > y)) { a[i] = y; a[ixj] = x; }
        }
      }
      __syncthreads();
    }
  }
}

// Wave-batch bitset greedy NMS over sorted candidates (single wave, no barriers).
__device__ __forceinline__ int bitset_scan(const u64* key_s, const float4* boxes4, size_t bbase,
                                           int C, float4* wbox, float4* bbox,
                                           float* outS, float* outB, int w, int wl) {
  int cur = 0;
  while (w < MAXT && cur < C) {
    int p = cur + wl;
    bool valid = (p < C);
    u64 kk = valid ? key_s[p] : 0ull;
    float4 mybox = make_float4(-3e30f, -3e30f, -3e30f, -3e30f);  // sentinel: zero overlap
    if (valid) {
      u32 idx = 0xFFFFFFFFu - (u32)(kk & 0xFFFFFFFFull);
      mybox = boxes4[bbase + idx];
    }
    bbox[wl] = mybox;
    float myarea = (mybox.z - mybox.x) * (mybox.w - mybox.y);
    bool alive = valid;
    for (int j = 0; j < w; ++j) {
      float4 pb = wbox[j];
      float yy1 = fmaxf(pb.x, mybox.x), xx1 = fmaxf(pb.y, mybox.y);
      float yy2 = fminf(pb.z, mybox.z), xx2 = fminf(pb.w, mybox.w);
      float inter = fmaxf(yy2 - yy1, 0.0f) * fmaxf(xx2 - xx1, 0.0f);
      bool bad = false;
      if (inter > 0.0f) {
        float pa = (pb.z - pb.x) * (pb.w - pb.y);
        bad = inter / (pa + myarea - inter + 1e-8f) > 0.3f;
      }
      alive = alive && !bad;
    }
    u64 krow = 0ull;
    int jmax = C - cur; if (jmax > 64) jmax = 64;
    for (int j = 0; j < jmax; ++j) {
      float4 pb = bbox[j];
      float yy1 = fmaxf(pb.x, mybox.x), xx1 = fmaxf(pb.y, mybox.y);
      float yy2 = fminf(pb.z, mybox.z), xx2 = fminf(pb.w, mybox.w);
      float inter = fmaxf(yy2 - yy1, 0.0f) * fmaxf(xx2 - xx1, 0.0f);
      bool kill = false;
      if (inter > 0.0f) {
        float pa = (pb.z - pb.x) * (pb.w - pb.y);
        kill = inter / (pa + myarea - inter + 1e-8f) > 0.3f;
      }
      if (kill) krow |= (1ull << j);
    }
    u32 krlo = (u32)krow, krhi = (u32)(krow >> 32);
    u64 amask = __ballot(alive);
    int myord = -1;
    while (amask != 0ull && w < MAXT) {
      int js = (int)__ffsll((unsigned long long)amask) - 1;
      u32 klo = __shfl(krlo, js, 64);
      u32 khi = __shfl(krhi, js, 64);
      u64 kr = ((u64)khi << 32) | (u64)klo;
      if (wl == js) myord = w;
      amask &= ~kr;
      amask &= ~(1ull << js);
      w++;
    }
    if (myord >= 0) {
      outS[myord] = __uint_as_float((u32)(kk >> 32));
      *(float4*)(outB + myord * 4) = mybox;
      wbox[myord] = mybox;
    }
    cur += 64;
  }
  return w;
}

// Wave-level lazy greedy NMS (fallback tier only; original semantics).
__device__ __forceinline__ int lazy_scan_g(const u64* key_s, const float4* boxes4, size_t bbase,
                                           int C, float4* wbox, float* outS, float* outB,
                                           int w, int wl) {
  int cur = 0;
  while (w < MAXT && cur < C) {
    int p = cur + wl;
    bool alive = (p < C);
    u64 kk = alive ? key_s[p] : 0ull;
    float4 mybox = make_float4(0.f, 0.f, 0.f, 0.f);
    if (alive) {
      u32 idx = 0xFFFFFFFFu - (u32)(kk & 0xFFFFFFFFull);
      mybox = boxes4[bbase + idx];
    }
    float myarea = (mybox.z - mybox.x) * (mybox.w - mybox.y);
    for (int j = 0; j < w; ++j) {
      float4 pb = wbox[j];
      float yy1 = fmaxf(pb.x, mybox.x), xx1 = fmaxf(pb.y, mybox.y);
      float yy2 = fminf(pb.z, mybox.z), xx2 = fminf(pb.w, mybox.w);
      float inter = fmaxf(yy2 - yy1, 0.0f) * fmaxf(xx2 - xx1, 0.0f);
      bool bad = false;
      if (inter > 0.0f) {
        float pa = (pb.z - pb.x) * (pb.w - pb.y);
        bad = inter / (pa + myarea - inter + 1e-8f) > 0.3f;
      }
      alive = alive && !bad;
    }
    for (;;) {
      u64 bal = __ballot(alive);
      if (bal == 0ull) break;
      int js = (int)__ffsll((unsigned long long)bal) - 1;
      float4 pb;
      pb.x = __shfl(mybox.x, js, 64);
      pb.y = __shfl(mybox.y, js, 64);
      pb.z = __shfl(mybox.z, js, 64);
      pb.w = __shfl(mybox.w, js, 64);
      u64 wk = __shfl(kk, js, 64);
      if (wl == 0) {
        outS[w] = __uint_as_float((u32)(wk >> 32));
        *(float4*)(outB + w * 4) = pb;
        wbox[w] = pb;
      }
      w++;
      if (w >= MAXT) break;
      if (wl <= js) alive = false;
      else if (alive) {
        float yy1 = fmaxf(pb.x, mybox.x), xx1 = fmaxf(pb.y, mybox.y);
        float yy2 = fminf(pb.z, mybox.z), xx2 = fminf(pb.w, mybox.w);
        float inter = fmaxf(yy2 - yy1, 0.0f) * fmaxf(xx2 - xx1, 0.0f);
        if (inter > 0.0f) {
          float pa = (pb.z - pb.x) * (pb.w - pb.y);
          if (inter / (pa + myarea - inter + 1e-8f) > 0.3f) alive = false;
        }
      }
    }
    cur += 64;
  }
  return w;
}

// ---------------- workspace zeroing ----------------
__global__ __launch_bounds__(256) void zero_kernel(u32* __restrict__ p, int n) {
  int i = blockIdx.x * 256 + threadIdx.x;
  if (i < n) p[i] = 0;
}

// ---------------- fused decode+clip (blocks 0..599) and streaming collect (600..7439) ----------------
__device__ __forceinline__ void coll_elem(int i, float x, int b, int base, int slice,
                                          u64* __restrict__ listT_g, u32* __restrict__ cnt_pad) {
  if (x >= 0.0f) {                  // s >= 0.5
    u32 a = (u32)i / 91u;           // compile-time magic-mul
    u32 c = (u32)i - a * 91u;
    if (c != 0u) {
      float s = 1.0f / (1.0f + expf(-x));
      int lane = b * NCLS + (int)c - 1;
      u32 idx = (u32)base + a;
      u32 p = atomicAdd(&cnt_pad[lane * 128 + slice * 16], 1u);
      if (p < SCAP) listT_g[(((size_t)lane * 8 + slice) << 9) + p] = pack_key(__float_as_uint(s), idx);
    }
  }
}

__global__ __launch_bounds__(256) void front_kernel(
    const float* __restrict__ bx0, const float* __restrict__ bx1, const float* __restrict__ bx2,
    const float* __restrict__ bx3, const float* __restrict__ bx4,
    const float* __restrict__ an0, const float* __restrict__ an1, const float* __restrict__ an2,
    const float* __restrict__ an3, const float* __restrict__ an4,
    const float* __restrict__ c3, const float* __restrict__ c4, const float* __restrict__ c5,
    const float* __restrict__ c6, const float* __restrict__ c7,
    const float* __restrict__ img, float* __restrict__ boxes,
    u64* __restrict__ listT_g, u32* __restrict__ cnt_pad)
{
  int blk = blockIdx.x, tid = threadIdx.x;
  if (blk < 600) {
    int t = blk * 256 + tid;
    if (t >= 2 * A_TOTAL) return;
    int b = t / A_TOTAL, a = t % A_TOTAL;
    const float* bp; const float* ap; int al; int nl;
    if (a < 57600)      { bp = bx0; ap = an0; al = a;          nl = 57600; }
    else if (a < 72000) { bp = bx1; ap = an1; al = a - 57600;  nl = 14400; }
    else if (a < 75600) { bp = bx2; ap = an2; al = a - 72000;  nl = 3600;  }
    else if (a < 76500) { bp = bx3; ap = an3; al = a - 75600;  nl = 900;   }
    else                { bp = bx4; ap = an4; al = a - 76500;  nl = 225;   }
    float4 e  = *(const float4*)(bp + ((size_t)b * nl + al) * 4);
    float4 an = *(const float4*)(ap + ((size_t)b * nl + al) * 4);
    const float CLIP = 4.135166556742356f; // log(1000/16)
    float ah  = an.z - an.x + 1.0f;
    float aw  = an.w - an.y + 1.0f;
    float ayc = an.x + 0.5f * ah;
    float axc = an.y + 0.5f * aw;
    float dh = fminf(e.z, CLIP), dw = fminf(e.w, CLIP);
    float yc = e.x * ah + ayc;
    float xc = e.y * aw + axc;
    float h  = expf(dh) * ah;
    float w  = expf(dw) * aw;
    float ymin = yc - 0.5f * h;
    float xmin = xc - 0.5f * w;
    float ymax = ymin + h - 1.0f;
    float xmax = xmin + w - 1.0f;
    float H = img[b * 2 + 0], W = img[b * 2 + 1];
    float4 o;
    o.x = fminf(fmaxf(ymin, 0.0f), H);
    o.y = fminf(fmaxf(xmin, 0.0f), W);
    o.z = fminf(fmaxf(ymax, 0.0f), H);
    o.w = fminf(fmaxf(xmax, 0.0f), W);
    *(float4*)(boxes + (size_t)t * 4) = o;
    return;
  }
  int blk2 = blk - 600;
  int slice = blk2 & 7;
  const float* cls; int n, base, b, loc, J, lvl;
  if (blk2 < 5120)      { lvl = 0; cls = c3; n = 57600; base = 0;     J = 2560; int r = blk2;        b = r >= J; loc = b ? r - J : r; }
  else if (blk2 < 6400) { lvl = 1; cls = c4; n = 14400; base = 57600; J = 640;  int r = blk2 - 5120; b = r >= J; loc = b ? r - J : r; }
  else if (blk2 < 6720) { lvl = 2; cls = c5; n = 3600;  base = 72000; J = 160;  int r = blk2 - 6400; b = r >= J; loc = b ? r - J : r; }
  else if (blk2 < 6800) { lvl = 3; cls = c6; n = 900;   base = 75600; J = 40;   int r = blk2 - 6720; b = r >= J; loc = b ? r - J : r; }
  else                  { lvl = 4; cls = c7; n = 225;   base = 76500; J = 20;   int r = blk2 - 6800; b = r >= J; loc = b ? r - J : r; }

  if (lvl <= 3) {
    int F4 = n * 91 / 4;
    int chunk = (F4 + J - 1) / J;
    int q0 = loc * chunk;
    int q1 = q0 + chunk; if (q1 > F4) q1 = F4;
    const float4* src4 = (const float4*)(cls + (size_t)b * n * 91);
    for (int q = q0 + tid; q < q1; q += 256) {
      float4 v = src4[q];
      int i0 = q << 2;
      coll_elem(i0,     v.x, b, base, slice, listT_g, cnt_pad);
      coll_elem(i0 + 1, v.y, b, base, slice, listT_g, cnt_pad);
      coll_elem(i0 + 2, v.z, b, base, slice, listT_g, cnt_pad);
      coll_elem(i0 + 3, v.w, b, base, slice, listT_g, cnt_pad);
    }
  } else {
    int F = n * 91;                 // 20475 (not /4-divisible) -> scalar
    int chunk = (F + J - 1) / J;
    int s0 = loc * chunk;
    int s1 = s0 + chunk; if (s1 > F) s1 = F;
    const float* src = cls + (size_t)b * F;
    for (int i = s0 + tid; i < s1; i += 256) coll_elem(i, src[i], b, base, slice, listT_g, cnt_pad);
  }
}

// ---------------- phase 1: per-lane top-8 prefix greedy -> true winner subset ----------------
__global__ __launch_bounds__(256) void top8_kernel(
    const u64* __restrict__ listT_g, const u32* __restrict__ cnt_pad,
    const float* __restrict__ boxes, u32* __restrict__ win8, u32* __restrict__ w8cnt)
{
  __shared__ u64 wred[4];
  __shared__ u64 sh_top;
  __shared__ u64 topk[8];
  __shared__ float4 tb[8];
  int tid = threadIdx.x;
  int lane = blockIdx.x;

  u32 pre[9]; pre[0] = 0;
  bool of = false;
  #pragma unroll
  for (int j = 0; j < 8; ++j) {
    u32 cj = cnt_pad[lane * 128 + j * 16];
    of |= (cj > SCAP);
    pre[j + 1] = pre[j] + cj;
  }
  u32 cnt = pre[8];
  if (of || cnt > TCAP) { if (tid == 0) w8cnt[lane] = 0xFFFFu; return; }

  u64 kr[8];
  #pragma unroll
  for (int r = 0; r < 8; ++r) {
    u32 s = (u32)tid + (u32)r * 256u;
    u64 k = 0ull;
    if (s < cnt) {
      u32 j = 0;
      #pragma unroll
      for (int t = 1; t < 8; ++t) if (s >= pre[t]) j = (u32)t;
      k = listT_g[(((size_t)lane * 8 + j) << 9) + (s - pre[j])];
    }
    kr[r] = k;
  }

  int nt = 0;
  for (int it = 0; it < 8; ++it) {
    u64 m = kr[0];
    #pragma unroll
    for (int r = 1; r < 8; ++r) if (kr[r] > m) m = kr[r];
    #pragma unroll
    for (int off = 1; off < 64; off <<= 1) {
      u64 o = __shfl_xor(m, off);
      if (o > m) m = o;
    }
    if ((tid & 63) == 0) wred[tid >> 6] = m;
    __syncthreads();
    if (tid == 0) {
      u64 w = wred[0];
      if (wred[1] > w) w = wred[1];
      if (wred[2] > w) w = wred[2];
      if (wred[3] > w) w = wred[3];
      sh_top = w;
      topk[it] = w;
    }
    __syncthreads();
    u64 ch = sh_top;
    if (ch == 0ull) break;
    #pragma unroll
    for (int r = 0; r < 8; ++r) if (kr[r] == ch) kr[r] = 0ull;   // keys unique
    nt = it + 1;
  }
  __syncthreads();
  const float4* boxes4 = (const float4*)boxes;
  size_t bbase = (size_t)(lane / NCLS) * A_TOTAL;
  if (tid < nt) {
    u32 idx = 0xFFFFFFFFu - (u32)(topk[tid] & 0xFFFFFFFFull);
    tb[tid] = boxes4[bbase + idx];
  }
  __syncthreads();
  if (tid == 0) {
    float4 abox[8];
    int w8 = 0;
    for (int i = 0; i < nt; ++i) {
      float4 mb = tb[i];
      float ma = (mb.z - mb.x) * (mb.w - mb.y);
      bool alive = true;
      for (int j = 0; j < w8; ++j) {
        float4 pb = abox[j];
        float yy1 = fmaxf(pb.x, mb.x), xx1 = fmaxf(pb.y, mb.y);
        float yy2 = fminf(pb.z, mb.z), xx2 = fminf(pb.w, mb.w);
        float inter = fmaxf(yy2 - yy1, 0.0f) * fmaxf(xx2 - xx1, 0.0f);
        if (inter > 0.0f) {
          float pa = (pb.z - pb.x) * (pb.w - pb.y);
          if (inter / (pa + ma - inter + 1e-8f) > 0.3f) alive = false;
        }
      }
      if (alive) {
        win8[lane * 8 + w8] = (u32)(topk[i] >> 32);
        abox[w8] = mb;
        w8++;
      }
    }
    w8cnt[lane] = (u32)w8;
  }
}

// ---------------- phase 2: per-batch T_b lower bound via 4096-bucket histogram ----------------
__global__ __launch_bounds__(256) void tlb2_kernel(const u32* __restrict__ win8,
                                                   const u32* __restrict__ w8cnt,
                                                   u32* __restrict__ tparams)
{
  __shared__ u32 hist[4096];
  __shared__ u32 sh_tot, sh_panic;
  __shared__ u32 sh_B, sh_total;
  int t = threadIdx.x;
  if (t == 0) sh_panic = 0;
  __syncthreads();
  for (int b = 0; b < 2; ++b) {
    for (int i = t; i < 4096; i += 256) hist[i] = 0;
    if (t == 0) sh_tot = 0;
    __syncthreads();
    u32 mycnt = 0;
    for (int i = t; i < 720; i += 256) {
      int ln = b * NCLS + i / 8;
      u32 cc = w8cnt[ln];
      if (cc == 0xFFFFu) { sh_panic = 1; }
      else if ((u32)(i & 7) < cc) {
        u32 v = win8[ln * 8 + (i & 7)];
        atomicAdd(&hist[v >> 19], 1u);
        mycnt++;
      }
    }
    atomicAdd(&sh_tot, mycnt);
    __syncthreads();
    if (t < 64) {
      u32 Bx, ix, ax, tx;
      cut4096w(hist, 100u, t, Bx, ix, ax, tx);
      if (t == 0) { sh_B = Bx; sh_total = tx; }
    }
    __syncthreads();
    if (t == 0) {
      tparams[b] = sh_B << 19;               // lower bound on 100th-largest winner score bits
      if (sh_tot < 100u || sh_total < 100u) sh_panic = 1;
    }
    __syncthreads();
  }
  if (t == 0) tparams[2] = sh_panic;
}

// ---------------- per-lane NMS: T_b fast path + exact in-kernel fallback ----------------
__global__ __launch_bounds__(256) void nms_kernel(
    const float* __restrict__ c3, const float* __restrict__ c4, const float* __restrict__ c5,
    const float* __restrict__ c6, const float* __restrict__ c7,
    const float* __restrict__ boxes, const u64* __restrict__ listT_g,
    const u32* __restrict__ cnt_pad, const u32* __restrict__ tparams,
    float* __restrict__ nms_s, float* __restrict__ nms_b)
{
  __shared__ __align__(16) char big[40960];     // fallback: listA u64[5120] -> cntArr u32[4096]
  __shared__ __align__(16) u64 listE[2048];     // fallback only
  __shared__ u64 key_s[2048];
  __shared__ __align__(16) u32 histL[4096];     // fallback hist; fast path: sel u64[SELCAP]
  __shared__ float4 wbox[MAXT];
  __shared__ float4 bbox[64];
  __shared__ u32 wtot[4];
  __shared__ u32 sh_flag, sh_cS;
  __shared__ u64 sh_minPrev;
  __shared__ u32 sh_w, sh_done, sh_eidx, sh_Rthr, sh_eSorted, sh_bigF;
  __shared__ u32 sh_B, sh_incl, sh_above, sh_total, sh_cA, sh_cE, sh_B2;

  int tid = threadIdx.x;
  int lane = blockIdx.x;
  int b = lane / NCLS, c = lane % NCLS;
  const float4* boxes4 = (const float4*)boxes;
  size_t bbase = (size_t)b * A_TOTAL;
  const u64 thrpack = ((u64)KTHR) << 32;

  float* outS = nms_s + (size_t)lane * MAXT;
  float* outB = nms_b + (size_t)lane * MAXT * 4;

  u32 pre[9]; pre[0] = 0;
  bool of = false;
  #pragma unroll
  for (int j = 0; j < 8; ++j) {
    u32 cj = cnt_pad[lane * 128 + j * 16];
    of |= (cj > SCAP);
    pre[j + 1] = pre[j] + cj;
  }
  u32 cnt = pre[8];
  u32 Tlb = tparams[b], panic = tparams[2];
  if (tid == 0) { sh_flag = (of || cnt > TCAP || panic) ? 1u : 0u; sh_cS = 0; }
  __syncthreads();

  if (!sh_flag) {
    // fast path: only candidates >= T_b can reach the final per-batch top-100
    const u64 Tpack = ((u64)Tlb) << 32;
    u64* sel = (u64*)histL;
    #pragma unroll
    for (int r = 0; r < 8; ++r) {
      u32 s = (u32)tid + (u32)r * 256u;
      if (s < cnt) {
        u32 j = 0;
        #pragma unroll
        for (int t = 1; t < 8; ++t) if (s >= pre[t]) j = (u32)t;
        u64 k = listT_g[(((size_t)lane * 8 + j) << 9) + (s - pre[j])];
        if (k >= Tpack) {
          u32 p = atomicAdd(&sh_cS, 1u);
          if (p < SELCAP) sel[p] = k;
        }
      }
    }
    __syncthreads();
    u32 Cs = sh_cS;
    if (Cs > SELCAP) {
      if (tid == 0) sh_flag = 1;
    } else {
      for (u32 j = tid; j < Cs; j += 256) {
        u64 kj = sel[j];
        u32 rk = 0;
        for (u32 i2 = 0; i2 < Cs; ++i2) rk += (sel[i2] > kj) ? 1u : 0u;
        key_s[rk] = kj;
      }
      __syncthreads();
      if (tid < 64) {
        int w = bitset_scan(key_s, boxes4, bbase, (int)Cs, wbox, bbox, outS, outB, 0, tid);
        if (tid == 0) sh_w = (u32)w;     // w < MAXT expected: rest provably below final top-100
      }
    }
  }
  __syncthreads();
  if (!sh_flag) {
    u32 w = sh_w;
    for (u32 p = w + (u32)tid; p < MAXT; p += 256) {
      outS[p] = -1.0f;
      *(float4*)(outB + p * 4) = make_float4(0.f, 0.f, 0.f, 0.f);
    }
    return;
  }

  // ================= EXACT FALLBACK (rare): rebuild from raw column =================
  auto sb_of = [&](int i) -> u32 {
    const float* p; int al, nl;
    if (i < 57600)      { p = c3; al = i;          nl = 57600; }
    else if (i < 72000) { p = c4; al = i - 57600;  nl = 14400; }
    else if (i < 75600) { p = c5; al = i - 72000;  nl = 3600;  }
    else if (i < 76500) { p = c6; al = i - 75600;  nl = 900;   }
    else                { p = c7; al = i - 76500;  nl = 225;   }
    float x = p[((size_t)b * nl + al) * 91 + (c + 1)];
    float s = 1.0f / (1.0f + expf(-x));
    return __float_as_uint(s);
  };

  u64* listA = (u64*)big;
  for (int i = tid; i < 4096; i += 256) histL[i] = 0;
  if (tid == 0) {
    sh_cA = 0; sh_cE = 0; sh_w = 0; sh_done = 0; sh_eidx = 0; sh_eSorted = 0; sh_minPrev = ~0ull;
  }
  __syncthreads();
  for (int i = tid; i < A_TOTAL; i += 256) atomicAdd(&histL[sb_of(i) >> 19], 1u);
  __syncthreads();
  if (tid < 64) {
    u32 Bx, ix, ax, tx;
    cut4096w(histL, KTOP, tid, Bx, ix, ax, tx);
    if (tid == 0) sh_B = Bx;
  }
  __syncthreads();
  u32 B = sh_B;
  for (int i = tid; i < A_TOTAL; i += 256) {
    u32 u = sb_of(i);
    u32 bkt = u >> 19;
    if (bkt > B) {
      u32 p = atomicAdd(&sh_cA, 1u);
      if (p < 5120u) listA[p] = pack_key(u, (u32)i);
    } else if (bkt == B) {
      u32 p = atomicAdd(&sh_cE, 1u);
      if (p < 2048u) listE[p] = pack_key(u, (u32)i);
    }
  }
  __syncthreads();
  u32 g = sh_cA, h = sh_cE;
  if (h > 2048u) {
    for (int i = tid; i < 4096; i += 256) histL[i] = 0;
    if (tid == 0) sh_cE = 0;
    __syncthreads();
    for (int i = tid; i < A_TOTAL; i += 256) {
      u32 u = sb_of(i);
      if ((u >> 19) == B) atomicAdd(&histL[(u >> 7) & 0xFFFu], 1u);
    }
    __syncthreads();
    u32 R1 = KTOP - g;
    if (tid < 64) {
      u32 Bx, ix, ax, tx;
      cut4096w(histL, R1, tid, Bx, ix, ax, tx);
      if (tid == 0) sh_B2 = Bx;
    }
    __syncthreads();
    u32 B2 = sh_B2;
    for (int i = tid; i < A_TOTAL; i += 256) {
      u32 u = sb_of(i);
      if ((u >> 19) == B) {
        u32 sb2 = (u >> 7) & 0xFFFu;
        if (sb2 > B2) {
          u32 p = atomicAdd(&sh_cA, 1u);
          if (p < 5120u) listA[p] = pack_key(u, (u32)i);
        } else if (sb2 == B2) {
          u32 p = atomicAdd(&sh_cE, 1u);
          if (p < 2048u) listE[p] = pack_key(u, (u32)i);
        }
      }
    }
    __syncthreads();
    g = sh_cA; h = sh_cE; if (h > 2048u) h = 2048u;
  }
  if (g > 5120u) g = 5120u;
  u32 R = (g < KTOP) ? (KTOP - g) : 0u; if (R > h) R = h;

  u64 ak[20];
  #pragma unroll
  for (int r = 0; r < 20; ++r) {
    u32 s2 = (u32)tid + (u32)r * 256u;
    u64 kp = (s2 < g) ? listA[s2] : 0ull;
    if (kp < thrpack) kp = 0ull;
    ak[r] = kp;
  }
  __syncthreads();
  u32* cntArr = (u32*)big;

  const float LO0  = 0.04f;
  const float INV0 = 4096.0f / (1.001f - 0.04f);

  for (int seg = 0; seg < 7200; ++seg) {
    __syncthreads();
    if (sh_w >= MAXT || sh_done) break;
    u64 minPrev = sh_minPrev;

    int digLvl = 0;
    u32 A_B0 = 0, A_B1 = 0;
    float lo1 = 0.f, inv1 = 0.f;
    u64 kMask = 0, kPref = 0;
    int m1shift = 32;
    int selMode = -1;
    u32 selB = 0;
    u32 C = 0;
    bool fromE = false;

    for (int lvl = 0; lvl < 8; ++lvl) {
      for (int i = tid; i < 4096; i += 256) histL[i] = 0;
      __syncthreads();
      #pragma unroll
      for (int r = 0; r < 20; ++r) {
        u64 k = ak[r];
        if (!k || k >= minPrev) continue;
        float s = __uint_as_float((u32)(k >> 32));
        if (digLvl >= 1) { int d0 = (int)((s - LO0) * INV0); d0 = min(max(d0, 0), 4095); if ((u32)d0 != A_B0) continue; }
        if (digLvl >= 2) { int d1 = (int)((s - lo1) * inv1); d1 = min(max(d1, 0), 4095); if ((u32)d1 != A_B1) continue; }
        if (digLvl >= 3 && ((k & kMask) != kPref)) continue;
        u32 d;
        if (digLvl == 0)      { int t0 = (int)((s - LO0) * INV0); d = (u32)min(max(t0, 0), 4095); }
        else if (digLvl == 1) { int t1 = (int)((s - lo1) * inv1); d = (u32)min(max(t1, 0), 4095); }
        else                  d = (u32)((k >> m1shift) & 0xFFFull);
        atomicAdd(&histL[d], 1u);
      }
      __syncthreads();
      if (tid < 64) {
        u32 Bx, ix, ax, tx;
        cut4096w(histL, 1024u, tid, Bx, ix, ax, tx);
        if (tid == 0) { sh_B = Bx; sh_incl = ix; sh_above = ax; sh_total = tx; }
      }
      __syncthreads();
      u32 total = sh_total, incl = sh_incl, above = sh_above, Bx = sh_B;
      if (total == 0u)   { fromE = true; break; }
      if (total < 1024u) { selMode = 0; C = total; break; }
      if (incl <= 2048u) { selMode = 1; selB = Bx; C = incl; break; }
      if (above > 0u)    { selMode = 2; selB = Bx; C = above; break; }
      if (digLvl == 0) {
        A_B0 = Bx;
        lo1 = LO0 + (float)Bx / INV0;
        inv1 = INV0 * 4096.0f;
        digLvl = 1;
      } else if (digLvl == 1) {
        A_B1 = Bx;
        digLvl = 2; m1shift = 32;
      } else {
        kPref |= ((u64)Bx << m1shift);
        kMask |= (0xFFFull << m1shift);
        m1shift -= 12;
        digLvl++;
      }
      __syncthreads();
    }

    if (fromE) {
      if (!sh_eSorted) {
        bitonic_desc(listE, h, tid, 256);
        if (tid == 0) {
          u32 lo = 0, hi2 = h;
          while (lo < hi2) { u32 mid = (lo + hi2) >> 1; if (listE[mid] >= thrpack) lo = mid + 1; else hi2 = mid; }
          sh_Rthr = (R < lo) ? R : lo;
          sh_eSorted = 1;
        }
        __syncthreads();
      }
      u32 eidx = sh_eidx;
      u32 take = (sh_Rthr > eidx) ? (sh_Rthr - eidx) : 0u;
      if (take > 2048u) take = 2048u;
      if (take == 0u) { if (tid == 0) sh_done = 1; continue; }
      for (u32 i = tid; i < take; i += 256) key_s[i] = listE[eidx + i];
      C = take;
      if (tid == 0) sh_eidx = eidx + take;
    } else {
      u32 hloc[16];
      {
        int t0 = tid << 4;
        u32 ssum = 0;
        #pragma unroll
        for (int j = 0; j < 16; ++j) { hloc[j] = histL[t0 + j]; ssum += hloc[j]; }
        int wl = tid & 63, wid = tid >> 6;
        u32 suf = ssum;
        #pragma unroll
        for (int off = 1; off < 64; off <<= 1) {
          u32 v = __shfl_down(suf, off, 64);
          if (wl < 64 - off) suf += v;
        }
        if (wl == 0) wtot[wid] = suf;
        __syncthreads();
        u32 cross = 0;
        for (int w2 = wid + 1; w2 < 4; ++w2) cross += wtot[w2];
        u32 run = (suf - ssum) + cross;
        #pragma unroll
        for (int j = 15; j >= 0; --j) { u32 base2 = run; run += hloc[j]; histL[t0 + j] = base2; }
      }
      for (int i = tid; i < 4096; i += 256) cntArr[i] = 0;
      if (tid == 0) sh_bigF = 0;
      __syncthreads();
      #pragma unroll
      for (int r = 0; r < 20; ++r) {
        u64 k = ak[r];
        if (!k || k >= minPrev) continue;
        float s = __uint_as_float((u32)(k >> 32));
        if (digLvl >= 1) { int d0 = (int)((s - LO0) * INV0); d0 = min(max(d0, 0), 4095); if ((u32)d0 != A_B0) continue; }
        if (digLvl >= 2) { int d1 = (int)((s - lo1) * inv1); d1 = min(max(d1, 0), 4095); if ((u32)d1 != A_B1) continue; }
        if (digLvl >= 3 && ((k & kMask) != kPref)) continue;
        u32 d;
        if (digLvl == 0)      { int t0x = (int)((s - LO0) * INV0); d = (u32)min(max(t0x, 0), 4095); }
        else if (digLvl == 1) { int t1x = (int)((s - lo1) * inv1); d = (u32)min(max(t1x, 0), 4095); }
        else                  d = (u32)((k >> m1shift) & 0xFFFull);
        if (selMode == 1)      { if (d < selB) continue; }
        else if (selMode == 2) { if (d <= selB) continue; }
        u32 pos = histL[d] + atomicAdd(&cntArr[d], 1u);
        if (pos < 2048u) key_s[pos] = k;
      }
      __syncthreads();
      {
        int t0 = tid << 4;
        for (int j = 0; j < 16; ++j) {
          u32 bkt = (u32)(t0 + j);
          u32 cc = cntArr[bkt];
          if (cc >= 2u) {
            if (cc <= 48u) {
              u32 basep = histL[bkt];
              for (u32 a2 = 1; a2 < cc; ++a2) {
                u64 kv = key_s[basep + a2];
                int bi = (int)a2 - 1;
                while (bi >= 0 && key_s[basep + bi] < kv) { key_s[basep + bi + 1] = key_s[basep + bi]; --bi; }
                key_s[basep + bi + 1] = kv;
              }
            } else sh_bigF = 1;
          }
        }
      }
      __syncthreads();
      if (sh_bigF) bitonic_desc(key_s, C, tid, 256);
      if (tid == 0) sh_minPrev = key_s[C - 1];
    }
    __syncthreads();

    if (tid < 64) {
      int w = lazy_scan_g(key_s, boxes4, bbase, (int)C, wbox, outS, outB, (int)sh_w, tid);
      if (tid == 0) sh_w = (u32)w;
    }
  }

  __syncthreads();
  u32 w = sh_w;
  for (u32 p = w + (u32)tid; p < MAXT; p += 256) {
    outS[p] = -1.0f;
    *(float4*)(outB + p * 4) = make_float4(0.f, 0.f, 0.f, 0.f);
  }
}

// ---------------- final per-batch top-100: radix rank-select ----------------
__global__ __launch_bounds__(256) void merge_kernel(
    const float* __restrict__ nms_s, const float* __restrict__ nms_b,
    float* __restrict__ out_b, float* __restrict__ out_s,
    float* __restrict__ out_c, float* __restrict__ out_v)
{
  __shared__ u64 keys[NCLS * MAXT];   // 72 KB
  __shared__ u32 hist[4096];          // 16 KB
  __shared__ u64 sel[640];
  __shared__ u32 sh_cnt, sh_valid;
  __shared__ u32 sh_B, sh_incl, sh_above, sh_total;

  int b = blockIdx.x, tid = threadIdx.x;
  const int NTOT = NCLS * MAXT;

  for (int i = tid; i < NTOT; i += 256) {
    float s = nms_s[(size_t)b * NTOT + i];
    u32 u = __float_as_uint(s);
    u = (u & 0x80000000u) ? ~u : (u | 0x80000000u);
    keys[i] = ((u64)u << 32) | (u64)(0xFFFFFFFFu - (u32)i);
  }
  if (tid == 0) { sh_cnt = 0; sh_valid = 0; }

  u64 prefVal = 0;
  u64 T = 0;
  u32 need = MAXT;
  const int shifts[6] = {52, 40, 28, 16, 4, 0};
  const int widths[6] = {12, 12, 12, 12, 12, 4};
  for (int lvl = 0; lvl < 6; ++lvl) {
    int s = shifts[lvl], w = widths[lvl];
    for (int i = tid; i < 4096; i += 256) hist[i] = 0;
    __syncthreads();
    u32 dmask = (1u << w) - 1u;
    for (int i = tid; i < NTOT; i += 256) {
      u64 k = keys[i];
      if (lvl > 0 && (k >> (s + w)) != (prefVal >> (s + w))) continue;
      atomicAdd(&hist[(u32)((k >> s) & dmask)], 1u);
    }
    __syncthreads();
    if (tid < 64) {
      u32 Bx, ix, ax, tx;
      cut4096w(hist, need, tid, Bx, ix, ax, tx);
      if (tid == 0) { sh_B = Bx; sh_incl = ix; sh_above = ax; sh_total = tx; }
    }
    __syncthreads();
    u32 B = sh_B, incl = sh_incl, above = sh_above;
    if (incl <= 512u || lvl == 5) {
      T = prefVal | ((u64)B << s);
      break;
    }
    prefVal |= ((u64)B << s);
    need -= above;
  }
  __syncthreads();

  for (int i = tid; i < NTOT; i += 256) {
    u64 k = keys[i];
    if (k >= T) {
      u32 p = atomicAdd(&sh_cnt, 1u);
      if (p < 640u) sel[p] = k;
    }
  }
  __syncthreads();
  u32 cnt = sh_cnt; if (cnt > 640u) cnt = 640u;

  for (u32 j = tid; j < cnt; j += 256) {
    u64 kj = sel[j];
    u32 r = 0;
    for (u32 i = 0; i < cnt; ++i) r += (sel[i] > kj) ? 1u : 0u;
    if (r < (u32)MAXT) {
      u32 u = (u32)(kj >> 32);
      u32 bits = (u & 0x80000000u) ? (u ^ 0x80000000u) : ~u;
      float sc = __uint_as_float(bits);
      u32 flat = 0xFFFFFFFFu - (u32)(kj & 0xFFFFFFFFull);
      int cls = (int)(flat / MAXT), pos = (int)(flat % MAXT);
      out_s[b * MAXT + r] = sc;
      out_c[b * MAXT + r] = (float)(cls + 1);
      *(float4*)(out_b + ((size_t)b * MAXT + r) * 4) =
          *(const float4*)(nms_b + (((size_t)b * NCLS + cls) * MAXT + pos) * 4);
      if (sc > -1.0f) atomicAdd(&sh_valid, 1u);
    }
  }
  __syncthreads();
  if (tid == 0) out_v[b] = (float)sh_valid;
}

extern "C" void kernel_launch(void* const* d_in, const int* in_sizes, int n_in,
                              void* d_out, int out_size, void* d_ws, size_t ws_size,
                              hipStream_t stream)
{
  const float* box[5]; const float* cls[5]; const float* anc[5];
  bool interleaved = (in_sizes[1] == 2 * 57600 * 91);   // setup_inputs dict order
  if (interleaved) {
    for (int l = 0; l < 5; ++l) {
      box[l] = (const float*)d_in[3 * l + 0];
      cls[l] = (const float*)d_in[3 * l + 1];
      anc[l] = (const float*)d_in[3 * l + 2];
    }
  } else {
    for (int l = 0; l < 5; ++l) {
      box[l] = (const float*)d_in[l];
      cls[l] = (const float*)d_in[5 + l];
      anc[l] = (const float*)d_in[10 + l];
    }
  }
  const float* img = (const float*)d_in[15];

  float* ws = (float*)d_ws;
  float* boxes_ws = ws;                              // 613800 f
  u32*   cnt_pad  = (u32*)(boxes_ws + 613800);       // 180*128 u32 (8 slices x 64B stride)
  u32*   win8     = cnt_pad + 180 * 128;             // 180*8 u32
  u32*   w8cnt    = win8 + 180 * 8;                  // 180 u32
  u32*   tparams  = w8cnt + 180;                     // 4 u32 (T0, T1, panic, pad)
  u64*   listT_g  = (u64*)(tparams + 4);             // 180*8*512 u64
  float* nms_s    = (float*)(listT_g + 180 * 8 * 512); // 18000 f
  float* nms_b    = nms_s + 18000;                   // 72000 f

  const int NZ = 180 * 128;
  zero_kernel<<<(NZ + 255) / 256, 256, 0, stream>>>(cnt_pad, NZ);

  front_kernel<<<7440, 256, 0, stream>>>(
      box[0], box[1], box[2], box[3], box[4],
      anc[0], anc[1], anc[2], anc[3], anc[4],
      cls[0], cls[1], cls[2], cls[3], cls[4],
      img, boxes_ws, listT_g, cnt_pad);

  top8_kernel<<<180, 256, 0, stream>>>(listT_g, cnt_pad, boxes_ws, win8, w8cnt);

  tlb2_kernel<<<1, 256, 0, stream>>>(win8, w8cnt, tparams);

  nms_kernel<<<180, 256, 0, stream>>>(cls[0], cls[1], cls[2], cls[3], cls[4],
                                      boxes_ws, listT_g, cnt_pad, tparams, nms_s, nms_b);

  float* out_b = (float*)d_out;  // [2][100][4]
  float* out_s = out_b + 800;    // [2][100]
  float* out_c = out_s + 200;    // [2][100]
  float* out_v = out_c + 200;    // [2]
  merge_kernel<<<2, 256, 0, stream>>>(nms_s, nms_b, out_b, out_s, out_c, out_v);
}